// Round 1
// baseline (1753.123 us; speedup 1.0000x reference)
//
#include <hip/hip_runtime.h>
#include <hip/hip_bf16.h>

#define N_NODES 100000
#define N_EDGES 3200000
#define F_IN    128
#define F_H     64

// ---------------------------------------------------------------------------
// deg / dinv
// ---------------------------------------------------------------------------
__global__ void k_init_deg(float* deg) {
    int i = blockIdx.x * blockDim.x + threadIdx.x;
    if (i < N_NODES) deg[i] = 1.0f;   // self-loop contributes 1
}

__global__ void k_count_deg(const int* __restrict__ dst, float* deg) {
    int e = blockIdx.x * blockDim.x + threadIdx.x;
    if (e < N_EDGES) atomicAdd(&deg[dst[e]], 1.0f);
}

__global__ void k_dinv(float* deg) {
    int i = blockIdx.x * blockDim.x + threadIdx.x;
    if (i < N_NODES) deg[i] = rsqrtf(deg[i]);   // deg >= 1 always
}

// ---------------------------------------------------------------------------
// Layer-1 GEMM: hs = (x @ W1^T) * dinv[node];  acc = hs  (self-loop init)
// block = 256 threads = 4 nodes x 64 out-features
// ---------------------------------------------------------------------------
__global__ void k_gemm1(const float* __restrict__ x, const float* __restrict__ W1,
                        const float* __restrict__ dinv,
                        float* __restrict__ hs, float* __restrict__ acc) {
    __shared__ float w[F_H * (F_IN + 1)];   // stride 129 -> bank (f+k)%32, 2-way max
    __shared__ float xr[4][F_IN];
    int t = threadIdx.x;
    for (int i = t; i < F_H * F_IN; i += 256) {
        int f = i >> 7, k = i & 127;
        w[f * (F_IN + 1) + k] = W1[i];
    }
    int node0 = blockIdx.x * 4;
    for (int i = t; i < 4 * F_IN; i += 256) {
        int n = i >> 7, k = i & 127;
        int node = node0 + n;
        xr[n][k] = (node < N_NODES) ? x[(long long)node * F_IN + k] : 0.0f;
    }
    __syncthreads();
    int n = t >> 6, f = t & 63;
    int node = node0 + n;
    if (node >= N_NODES) return;
    float s = 0.0f;
#pragma unroll
    for (int k = 0; k < F_IN; k++) s += xr[n][k] * w[f * (F_IN + 1) + k];
    float v = s * dinv[node];
    hs[(long long)node * F_H + f]  = v;
    acc[(long long)node * F_H + f] = v;
}

// ---------------------------------------------------------------------------
// Scatter: acc[dst] += hs[src], one wave (64 lanes) per edge
// ---------------------------------------------------------------------------
__global__ void k_scatter(const int* __restrict__ src, const int* __restrict__ dst,
                          const float* __restrict__ hs, float* __restrict__ acc) {
    unsigned tid = blockIdx.x * blockDim.x + threadIdx.x;
    unsigned e = tid >> 6;
    int f = tid & 63;
    if (e >= N_EDGES) return;
    int s = src[e], d = dst[e];
    float v = hs[(long long)s * F_H + f];
    atomicAdd(&acc[(long long)d * F_H + f], v);
}

// ---------------------------------------------------------------------------
// Layer-1 epilogue + Layer-2 GEMM (fused):
//   z     = relu(dinv*acc1 + b1)
//   hs2   = (z @ W2^T) * dinv
//   acc2  = hs2 (self-loop init)   -- acc2 may alias acc1 (row-exclusive blocks)
// ---------------------------------------------------------------------------
__global__ void k_gemm2(const float* __restrict__ W2, const float* __restrict__ b1,
                        const float* __restrict__ dinv,
                        float* accio /* in: acc1, out: acc2 (same buffer ok) */,
                        float* __restrict__ hs2) {
    __shared__ float w[F_H * (F_H + 1)];    // stride 65 -> conflict-free
    __shared__ float z[4][F_H];
    int t = threadIdx.x;
    for (int i = t; i < F_H * F_H; i += 256) {
        int f = i >> 6, k = i & 63;
        w[f * (F_H + 1) + k] = W2[i];
    }
    int node0 = blockIdx.x * 4;
    int n = t >> 6, f = t & 63;
    int node = node0 + n;
    float di = 0.0f;
    if (node < N_NODES) {
        di = dinv[node];
        float zz = di * accio[(long long)node * F_H + f] + b1[f];
        z[n][f] = fmaxf(zz, 0.0f);
    }
    __syncthreads();
    if (node >= N_NODES) return;
    float s = 0.0f;
#pragma unroll
    for (int k = 0; k < F_H; k++) s += z[n][k] * w[f * (F_H + 1) + k];
    float v = s * di;
    hs2[(long long)node * F_H + f]   = v;
    accio[(long long)node * F_H + f] = v;   // write strictly after all reads (barrier)
}

// ---------------------------------------------------------------------------
// Head: out[i] = dot(dinv[i]*acc2[i] + b2, Wc) + bc   (wave-64 reduce)
// ---------------------------------------------------------------------------
__global__ void k_final(const float* __restrict__ acc2, const float* __restrict__ dinv,
                        const float* __restrict__ b2, const float* __restrict__ Wc,
                        const float* __restrict__ bc, float* __restrict__ out) {
    unsigned tid = blockIdx.x * blockDim.x + threadIdx.x;
    unsigned node = tid >> 6;
    int f = tid & 63;
    if (node >= N_NODES) return;
    float v = (dinv[node] * acc2[(long long)node * F_H + f] + b2[f]) * Wc[f];
#pragma unroll
    for (int off = 32; off > 0; off >>= 1)
        v += __shfl_xor(v, off, 64);
    if (f == 0) out[node] = v + bc[0];
}

// ---------------------------------------------------------------------------
extern "C" void kernel_launch(void* const* d_in, const int* in_sizes, int n_in,
                              void* d_out, int out_size, void* d_ws, size_t ws_size,
                              hipStream_t stream) {
    const float* x  = (const float*)d_in[0];
    const int*   ei = (const int*)d_in[1];
    const int*   src = ei;
    const int*   dst = ei + N_EDGES;
    const float* W1 = (const float*)d_in[2];
    const float* b1 = (const float*)d_in[3];
    const float* W2 = (const float*)d_in[4];
    const float* b2 = (const float*)d_in[5];
    const float* Wc = (const float*)d_in[6];
    const float* bc = (const float*)d_in[7];
    float* out = (float*)d_out;

    float* ws   = (float*)d_ws;
    float* dinv = ws;                       // N floats (deg -> dinv in place)
    float* bufA = ws + N_NODES;             // hs   (25.6 MB)
    float* bufB = bufA + (long long)N_NODES * F_H;  // acc (25.6 MB)

    const int TB = 256;
    k_init_deg <<<(N_NODES + TB - 1) / TB, TB, 0, stream>>>(dinv);
    k_count_deg<<<(N_EDGES + TB - 1) / TB, TB, 0, stream>>>(dst, dinv);
    k_dinv     <<<(N_NODES + TB - 1) / TB, TB, 0, stream>>>(dinv);

    // layer 1
    k_gemm1<<<(N_NODES + 3) / 4, TB, 0, stream>>>(x, W1, dinv, bufA, bufB);
    k_scatter<<<((unsigned)N_EDGES * 64 + TB - 1) / TB, TB, 0, stream>>>(src, dst, bufA, bufB);

    // layer 2 (epilogue1 + gemm2 fused; acc in-place, hs2 reuses bufA)
    k_gemm2<<<(N_NODES + 3) / 4, TB, 0, stream>>>(W2, b1, dinv, bufB, bufA);
    k_scatter<<<((unsigned)N_EDGES * 64 + TB - 1) / TB, TB, 0, stream>>>(src, dst, bufA, bufB);

    // head
    k_final<<<((unsigned)N_NODES * 64 + TB - 1) / TB, TB, 0, stream>>>(bufB, dinv, b2, Wc, bc, out);
}

// Round 2
// 1289.657 us; speedup vs baseline: 1.3594x; 1.3594x over previous
//
#include <hip/hip_runtime.h>
#include <hip/hip_bf16.h>

#define N_NODES 100000
#define N_EDGES 3200000
#define F_IN    128
#define F_H     64

// ---------------------------------------------------------------------------
// CSR build: histogram of dst -> exclusive scan -> counting-sort fill
// ---------------------------------------------------------------------------
__global__ void k_hist(const int* __restrict__ dst, int* __restrict__ counts) {
    int e = blockIdx.x * blockDim.x + threadIdx.x;
    if (e < N_EDGES) atomicAdd(&counts[dst[e]], 1);
}

// single block, 1024 threads: exclusive scan of counts -> row_ptr & cursor,
// plus dinv = rsqrt(counts+1)  (self-loop adds 1 to degree)
#define SCAN_T 1024
__global__ void k_scan(const int* __restrict__ counts, int* __restrict__ row_ptr,
                       int* __restrict__ cursor, float* __restrict__ dinv) {
    __shared__ int ps[SCAN_T];
    int t = threadIdx.x;
    const int chunk = (N_NODES + SCAN_T - 1) / SCAN_T;   // 98
    int beg = t * chunk;
    int end = min(beg + chunk, N_NODES);
    int s = 0;
    for (int i = beg; i < end; i++) s += counts[i];
    ps[t] = s;
    __syncthreads();
    // inclusive Hillis-Steele scan over 1024 partials
    for (int off = 1; off < SCAN_T; off <<= 1) {
        int v = (t >= off) ? ps[t - off] : 0;
        __syncthreads();
        ps[t] += v;
        __syncthreads();
    }
    int off = (t == 0) ? 0 : ps[t - 1];
    for (int i = beg; i < end; i++) {
        int c = counts[i];
        row_ptr[i] = off;
        cursor[i]  = off;
        dinv[i] = rsqrtf((float)(c + 1));
        off += c;
    }
    if (beg < N_NODES && end == N_NODES) row_ptr[N_NODES] = off;  // = N_EDGES
}

__global__ void k_fill(const int* __restrict__ src, const int* __restrict__ dst,
                       int* __restrict__ cursor, int* __restrict__ srcs_sorted) {
    int e = blockIdx.x * blockDim.x + threadIdx.x;
    if (e < N_EDGES) {
        int pos = atomicAdd(&cursor[dst[e]], 1);
        srcs_sorted[pos] = src[e];
    }
}

// ---------------------------------------------------------------------------
// Layer-1 GEMM: hs = (x @ W1^T) * dinv[node]
// block = 256 threads = 4 nodes x 64 out-features
// ---------------------------------------------------------------------------
__global__ void k_gemm1(const float* __restrict__ x, const float* __restrict__ W1,
                        const float* __restrict__ dinv, float* __restrict__ hs) {
    __shared__ float w[F_H * (F_IN + 1)];
    __shared__ float xr[4][F_IN];
    int t = threadIdx.x;
    for (int i = t; i < F_H * F_IN; i += 256) {
        int f = i >> 7, k = i & 127;
        w[f * (F_IN + 1) + k] = W1[i];
    }
    int node0 = blockIdx.x * 4;
    for (int i = t; i < 4 * F_IN; i += 256) {
        int n = i >> 7, k = i & 127;
        int node = node0 + n;
        xr[n][k] = (node < N_NODES) ? x[(size_t)node * F_IN + k] : 0.0f;
    }
    __syncthreads();
    int n = t >> 6, f = t & 63;
    int node = node0 + n;
    if (node >= N_NODES) return;
    float s = 0.0f;
#pragma unroll
    for (int k = 0; k < F_IN; k++) s += xr[n][k] * w[f * (F_IN + 1) + k];
    hs[(size_t)node * F_H + f] = s * dinv[node];
}

// ---------------------------------------------------------------------------
// Aggregate layer 1 (gather, no atomics) + epilogue: z = relu(dinv*agg + b1)
// one wave per node, lane = feature
// ---------------------------------------------------------------------------
__global__ void k_agg1(const int* __restrict__ row_ptr, const int* __restrict__ srcs,
                       const float* __restrict__ hs, const float* __restrict__ dinv,
                       const float* __restrict__ b1, float* __restrict__ z) {
    unsigned tid = blockIdx.x * blockDim.x + threadIdx.x;
    unsigned node = tid >> 6;
    int f = tid & 63;
    if (node >= N_NODES) return;
    int beg = row_ptr[node], end = row_ptr[node + 1];
    float v = hs[(size_t)node * F_H + f];          // self-loop
    int j = beg;
    for (; j + 1 < end; j += 2) {                  // 2 loads in flight
        int s0 = srcs[j], s1 = srcs[j + 1];
        float a = hs[(size_t)s0 * F_H + f];
        float b = hs[(size_t)s1 * F_H + f];
        v += a; v += b;
    }
    if (j < end) v += hs[(size_t)srcs[j] * F_H + f];
    z[(size_t)node * F_H + f] = fmaxf(dinv[node] * v + b1[f], 0.0f);
}

// ---------------------------------------------------------------------------
// Layer-2 GEMM (in place): zio <- (zio @ W2^T) * dinv
// block reads only its own 4 rows, barrier, writes same rows -> alias-safe
// ---------------------------------------------------------------------------
__global__ void k_gemm2(const float* __restrict__ W2, const float* __restrict__ dinv,
                        float* zio) {
    __shared__ float w[F_H * (F_H + 1)];
    __shared__ float zr[4][F_H];
    int t = threadIdx.x;
    for (int i = t; i < F_H * F_H; i += 256) {
        int f = i >> 6, k = i & 63;
        w[f * (F_H + 1) + k] = W2[i];
    }
    int node0 = blockIdx.x * 4;
    int n = t >> 6, f = t & 63;
    int node = node0 + n;
    if (node < N_NODES) zr[n][f] = zio[(size_t)node * F_H + f];
    __syncthreads();
    if (node >= N_NODES) return;
    float s = 0.0f;
#pragma unroll
    for (int k = 0; k < F_H; k++) s += zr[n][k] * w[f * (F_H + 1) + k];
    zio[(size_t)node * F_H + f] = s * dinv[node];
}

// ---------------------------------------------------------------------------
// Aggregate layer 2 + head (fused): out = dot(dinv*agg + b2, Wc) + bc
// ---------------------------------------------------------------------------
__global__ void k_agg2_head(const int* __restrict__ row_ptr, const int* __restrict__ srcs,
                            const float* __restrict__ hs2, const float* __restrict__ dinv,
                            const float* __restrict__ b2, const float* __restrict__ Wc,
                            const float* __restrict__ bc, float* __restrict__ out) {
    unsigned tid = blockIdx.x * blockDim.x + threadIdx.x;
    unsigned node = tid >> 6;
    int f = tid & 63;
    if (node >= N_NODES) return;
    int beg = row_ptr[node], end = row_ptr[node + 1];
    float v = hs2[(size_t)node * F_H + f];         // self-loop
    int j = beg;
    for (; j + 1 < end; j += 2) {
        int s0 = srcs[j], s1 = srcs[j + 1];
        float a = hs2[(size_t)s0 * F_H + f];
        float b = hs2[(size_t)s1 * F_H + f];
        v += a; v += b;
    }
    if (j < end) v += hs2[(size_t)srcs[j] * F_H + f];
    float r = (dinv[node] * v + b2[f]) * Wc[f];
#pragma unroll
    for (int off = 32; off > 0; off >>= 1)
        r += __shfl_xor(r, off, 64);
    if (f == 0) out[node] = r + bc[0];
}

// ---------------------------------------------------------------------------
extern "C" void kernel_launch(void* const* d_in, const int* in_sizes, int n_in,
                              void* d_out, int out_size, void* d_ws, size_t ws_size,
                              hipStream_t stream) {
    const float* x  = (const float*)d_in[0];
    const int*   ei = (const int*)d_in[1];
    const int*   src = ei;
    const int*   dst = ei + N_EDGES;
    const float* W1 = (const float*)d_in[2];
    const float* b1 = (const float*)d_in[3];
    const float* W2 = (const float*)d_in[4];
    const float* b2 = (const float*)d_in[5];
    const float* Wc = (const float*)d_in[6];
    const float* bc = (const float*)d_in[7];
    float* out = (float*)d_out;

    // workspace carve-up (bytes)
    char* w = (char*)d_ws;
    int*   counts  = (int*)w;                          w += (size_t)N_NODES * 4;
    int*   cursor  = (int*)w;                          w += (size_t)N_NODES * 4;
    int*   row_ptr = (int*)w;                          w += ((size_t)N_NODES + 4) * 4;
    float* dinv    = (float*)w;                        w += (size_t)N_NODES * 4;
    int*   srcs    = (int*)w;                          w += (size_t)N_EDGES * 4;
    float* bufA    = (float*)w;                        w += (size_t)N_NODES * F_H * 4;  // hs1
    float* bufB    = (float*)w;                        w += (size_t)N_NODES * F_H * 4;  // z / hs2

    const int TB = 256;
    hipMemsetAsync(counts, 0, (size_t)N_NODES * 4, stream);
    k_hist<<<(N_EDGES + TB - 1) / TB, TB, 0, stream>>>(dst, counts);
    k_scan<<<1, SCAN_T, 0, stream>>>(counts, row_ptr, cursor, dinv);
    k_fill<<<(N_EDGES + TB - 1) / TB, TB, 0, stream>>>(src, dst, cursor, srcs);

    // layer 1
    k_gemm1<<<(N_NODES + 3) / 4, TB, 0, stream>>>(x, W1, dinv, bufA);
    k_agg1<<<((unsigned)N_NODES * 64 + TB - 1) / TB, TB, 0, stream>>>(row_ptr, srcs, bufA, dinv, b1, bufB);

    // layer 2 (gemm in place on bufB)
    k_gemm2<<<(N_NODES + 3) / 4, TB, 0, stream>>>(W2, dinv, bufB);
    k_agg2_head<<<((unsigned)N_NODES * 64 + TB - 1) / TB, TB, 0, stream>>>(row_ptr, srcs, bufB, dinv, b2, Wc, bc, out);
}

// Round 3
// 836.406 us; speedup vs baseline: 2.0960x; 1.5419x over previous
//
#include <hip/hip_runtime.h>
#include <hip/hip_bf16.h>

#define N_NODES 100000
#define N_EDGES 3200000
#define F_IN    128
#define F_H     64

#define NBUCK 256
#define NPB   391            // ceil(N_NODES / NBUCK); last bucket short

// ---------------------------------------------------------------------------
// degree histogram
// ---------------------------------------------------------------------------
__global__ void k_hist(const int* __restrict__ dst, int* __restrict__ counts) {
    int e = blockIdx.x * blockDim.x + threadIdx.x;
    if (e < N_EDGES) atomicAdd(&counts[dst[e]], 1);
}

// ---------------------------------------------------------------------------
// 3-phase exclusive scan over counts[N] -> row_ptr, plus cursor/dinv/bucket bases
// ---------------------------------------------------------------------------
#define SC_CHUNK 1000
#define SC_T     1024
__global__ __launch_bounds__(SC_T) void k_scan1(const int* __restrict__ counts,
                                                int* __restrict__ row_ptr,
                                                int* __restrict__ partials) {
    __shared__ int s[SC_T];
    int t = threadIdx.x;
    int node = blockIdx.x * SC_CHUNK + t;
    int c = (t < SC_CHUNK) ? counts[node] : 0;
    s[t] = c;
    __syncthreads();
    for (int off = 1; off < SC_T; off <<= 1) {
        int v = (t >= off) ? s[t - off] : 0;
        __syncthreads();
        s[t] += v;
        __syncthreads();
    }
    if (t < SC_CHUNK) row_ptr[node] = s[t] - c;   // local exclusive
    if (t == SC_T - 1) partials[blockIdx.x] = s[t];
}

__global__ __launch_bounds__(128) void k_scan2(int* __restrict__ partials,
                                               int* __restrict__ row_ptr) {
    __shared__ int s[128];
    int t = threadIdx.x;
    const int NB = (N_NODES + SC_CHUNK - 1) / SC_CHUNK;   // 100
    int c = (t < NB) ? partials[t] : 0;
    s[t] = c;
    __syncthreads();
    for (int off = 1; off < 128; off <<= 1) {
        int v = (t >= off) ? s[t - off] : 0;
        __syncthreads();
        s[t] += v;
        __syncthreads();
    }
    if (t < NB) partials[t] = s[t] - c;           // exclusive base per block
    if (t == 127) row_ptr[N_NODES] = s[127];      // total = N_EDGES
}

__global__ __launch_bounds__(SC_T) void k_scan3(const int* __restrict__ counts,
                                                const int* __restrict__ partials,
                                                int* __restrict__ row_ptr,
                                                int* __restrict__ cursor,
                                                float* __restrict__ dinv,
                                                int* __restrict__ bucket_cursor) {
    int t = threadIdx.x;
    if (t >= SC_CHUNK) return;
    int node = blockIdx.x * SC_CHUNK + t;
    int r = row_ptr[node] + partials[blockIdx.x];
    row_ptr[node] = r;
    cursor[node]  = r;
    dinv[node] = rsqrtf((float)(counts[node] + 1));
    if (node % NPB == 0) bucket_cursor[node / NPB] = r;
}

// ---------------------------------------------------------------------------
// Pass A: partition edges into NBUCK dst-range buckets (LDS-staged, coalesced out)
// ---------------------------------------------------------------------------
#define PA_T   256
#define PA_C   4096
#define PA_PER (PA_C / PA_T)   // 16
__global__ __launch_bounds__(PA_T) void k_partA(const int* __restrict__ src,
                                                const int* __restrict__ dst,
                                                int* __restrict__ bucket_cursor,
                                                int* __restrict__ srcT,
                                                int* __restrict__ dstT) {
    __shared__ int lcount[NBUCK];
    __shared__ int lstart[NBUCK];
    __shared__ int loffs[NBUCK];
    __shared__ int lbase[NBUCK];
    __shared__ int s_src[PA_C];
    __shared__ int s_dst[PA_C];
    __shared__ unsigned char s_bkt[PA_C];
    __shared__ int ltot;
    int t = threadIdx.x;
    long long e0 = (long long)blockIdx.x * PA_C;
    if (t < NBUCK) lcount[t] = 0;
    __syncthreads();
    int es[PA_PER], ed[PA_PER];
    short eb[PA_PER];
#pragma unroll
    for (int i = 0; i < PA_PER; i++) {
        long long e = e0 + i * PA_T + t;
        if (e < N_EDGES) {
            es[i] = src[e]; ed[i] = dst[e];
            int b = ed[i] / NPB;
            eb[i] = (short)b;
            atomicAdd(&lcount[b], 1);
        } else eb[i] = -1;
    }
    __syncthreads();
    // exclusive scan of lcount (256) by wave 0: 4 serial/lane + shfl scan
    if (t < 64) {
        int base = t * 4;
        int c0 = lcount[base], c1 = lcount[base + 1], c2 = lcount[base + 2], c3 = lcount[base + 3];
        int ssum = c0 + c1 + c2 + c3;
        int sc = ssum;
#pragma unroll
        for (int off = 1; off < 64; off <<= 1) {
            int v = __shfl_up(sc, off, 64);
            if (t >= off) sc += v;
        }
        int ex = sc - ssum;
        lstart[base]     = ex;
        lstart[base + 1] = ex + c0;
        lstart[base + 2] = ex + c0 + c1;
        lstart[base + 3] = ex + c0 + c1 + c2;
        if (t == 63) ltot = sc;
    }
    __syncthreads();
    if (t < NBUCK) {
        loffs[t] = lstart[t];
        int c = lcount[t];
        lbase[t] = c ? atomicAdd(&bucket_cursor[t], c) : 0;
    }
    __syncthreads();
#pragma unroll
    for (int i = 0; i < PA_PER; i++) {
        if (eb[i] >= 0) {
            int idx = atomicAdd(&loffs[eb[i]], 1);
            s_src[idx] = es[i];
            s_dst[idx] = ed[i];
            s_bkt[idx] = (unsigned char)eb[i];
        }
    }
    __syncthreads();
    int tot = ltot;
    for (int i = t; i < tot; i += PA_T) {
        int b = s_bkt[i];
        int addr = lbase[b] + (i - lstart[b]);
        srcT[addr] = s_src[i];
        dstT[addr] = s_dst[i];
    }
}

// ---------------------------------------------------------------------------
// Pass B: per-bucket LDS counting sort -> final srcs[] segment (coalesced)
// ---------------------------------------------------------------------------
#define PB_T   1024
#define PB_CAP 16384
__global__ __launch_bounds__(PB_T) void k_partB(const int* __restrict__ row_ptr,
                                                const int* __restrict__ srcT,
                                                const int* __restrict__ dstT,
                                                int* __restrict__ cursor,
                                                int* __restrict__ srcs) {
    __shared__ int lhist[NPB];
    __shared__ int lcur[NPB];
    __shared__ int s_out[PB_CAP];
    int b = blockIdx.x;
    int node0 = b * NPB;
    int node1 = min(node0 + NPB, N_NODES);
    int beg = row_ptr[node0];
    int end = row_ptr[node1];
    int len = end - beg;
    int t = threadIdx.x;
    if (len <= PB_CAP) {
        for (int i = t; i < NPB; i += PB_T) lhist[i] = 0;
        __syncthreads();
        for (int i = t; i < len; i += PB_T)
            atomicAdd(&lhist[dstT[beg + i] - node0], 1);
        __syncthreads();
        if (t < 64) {   // exclusive scan of 391 counters: 7/lane + shfl
            int base = t * 7;
            int c[7]; int ssum = 0;
#pragma unroll
            for (int j = 0; j < 7; j++) {
                int idx = base + j;
                c[j] = (idx < NPB) ? lhist[idx] : 0;
                ssum += c[j];
            }
            int sc = ssum;
#pragma unroll
            for (int off = 1; off < 64; off <<= 1) {
                int v = __shfl_up(sc, off, 64);
                if (t >= off) sc += v;
            }
            int ex = sc - ssum;
#pragma unroll
            for (int j = 0; j < 7; j++) {
                int idx = base + j;
                if (idx < NPB) lcur[idx] = ex;
                ex += c[j];
            }
        }
        __syncthreads();
        for (int i = t; i < len; i += PB_T) {
            int d = dstT[beg + i] - node0;
            int sv = srcT[beg + i];
            int idx = atomicAdd(&lcur[d], 1);
            s_out[idx] = sv;
        }
        __syncthreads();
        for (int i = t; i < len; i += PB_T)
            srcs[beg + i] = s_out[i];
    } else {            // statistically never: safe fallback via global cursors
        for (int i = t; i < len; i += PB_T) {
            int d = dstT[beg + i];
            int pos = atomicAdd(&cursor[d], 1);
            srcs[pos] = srcT[beg + i];
        }
    }
}

// ---------------------------------------------------------------------------
// Layer-1 GEMM: hs = (x @ W1^T) * dinv ; 16 nodes/block, 1 wave per node
// ---------------------------------------------------------------------------
#define G1_T 1024
#define G1_N 16
#define W1S  140    // stride: ≡12 mod 32 words, 16B-aligned rows
__global__ __launch_bounds__(G1_T) void k_gemm1(const float* __restrict__ x,
                                                const float* __restrict__ W1,
                                                const float* __restrict__ dinv,
                                                float* __restrict__ hs) {
    __shared__ float w[F_H * W1S];        // ~35 KB
    __shared__ float xr[G1_N][F_IN];      // 8 KB
    int t = threadIdx.x;
    for (int i = t; i < F_H * F_IN / 4; i += G1_T) {
        float4 v = ((const float4*)W1)[i];
        int f = (i * 4) >> 7, k = (i * 4) & 127;
        *(float4*)&w[f * W1S + k] = v;
    }
    int node0 = blockIdx.x * G1_N;
    for (int i = t; i < G1_N * F_IN / 4; i += G1_T) {
        int n = (i * 4) >> 7, k = (i * 4) & 127;
        int node = node0 + n;
        float4 v = make_float4(0.f, 0.f, 0.f, 0.f);
        if (node < N_NODES) v = ((const float4*)x)[((size_t)node * F_IN + k) >> 2];
        *(float4*)&xr[n][k] = v;
    }
    __syncthreads();
    int n = t >> 6, f = t & 63;
    int node = node0 + n;
    if (node >= N_NODES) return;
    float4 acc = make_float4(0.f, 0.f, 0.f, 0.f);
#pragma unroll
    for (int k = 0; k < F_IN; k += 4) {
        float4 wv = *(const float4*)&w[f * W1S + k];
        float4 xv = *(const float4*)&xr[n][k];
        acc.x += wv.x * xv.x; acc.y += wv.y * xv.y;
        acc.z += wv.z * xv.z; acc.w += wv.w * xv.w;
    }
    float s = (acc.x + acc.y) + (acc.z + acc.w);
    hs[(size_t)node * F_H + f] = s * dinv[node];
}

// ---------------------------------------------------------------------------
// Aggregate L1 + epilogue: z = relu(dinv * (self + sum_neighbors) + b1)
// ---------------------------------------------------------------------------
__global__ void k_agg1(const int* __restrict__ row_ptr, const int* __restrict__ srcs,
                       const float* __restrict__ hs, const float* __restrict__ dinv,
                       const float* __restrict__ b1, float* __restrict__ z) {
    unsigned tid = blockIdx.x * blockDim.x + threadIdx.x;
    unsigned node = tid >> 6;
    int f = tid & 63;
    if (node >= N_NODES) return;
    int beg = row_ptr[node], end = row_ptr[node + 1];
    float v = hs[(size_t)node * F_H + f];
    int j = beg;
    for (; j + 4 <= end; j += 4) {
        int s0 = srcs[j], s1 = srcs[j + 1], s2 = srcs[j + 2], s3 = srcs[j + 3];
        float a = hs[(size_t)s0 * F_H + f];
        float b = hs[(size_t)s1 * F_H + f];
        float c = hs[(size_t)s2 * F_H + f];
        float d = hs[(size_t)s3 * F_H + f];
        v += (a + b) + (c + d);
    }
    for (; j < end; j++) v += hs[(size_t)srcs[j] * F_H + f];
    z[(size_t)node * F_H + f] = fmaxf(dinv[node] * v + b1[f], 0.0f);
}

// ---------------------------------------------------------------------------
// Layer-2 GEMM (in place): zio <- (zio @ W2^T) * dinv ; 16 nodes/block
// ---------------------------------------------------------------------------
#define G2_T 1024
#define G2_N 16
#define W2S  76     // ≡12 mod 32, 16B-aligned
__global__ __launch_bounds__(G2_T) void k_gemm2(const float* __restrict__ W2,
                                                const float* __restrict__ dinv,
                                                float* zio) {
    __shared__ float w[F_H * W2S];
    __shared__ float zr[G2_N][F_H];
    int t = threadIdx.x;
    for (int i = t; i < F_H * F_H / 4; i += G2_T) {
        float4 v = ((const float4*)W2)[i];
        int f = (i * 4) >> 6, k = (i * 4) & 63;
        *(float4*)&w[f * W2S + k] = v;
    }
    int node0 = blockIdx.x * G2_N;
    int n = t >> 6, f = t & 63;
    int node = node0 + n;
    if (node < N_NODES) zr[n][f] = zio[(size_t)node * F_H + f];
    __syncthreads();
    if (node >= N_NODES) return;
    float4 acc = make_float4(0.f, 0.f, 0.f, 0.f);
#pragma unroll
    for (int k = 0; k < F_H; k += 4) {
        float4 wv = *(const float4*)&w[f * W2S + k];
        float4 zv = *(const float4*)&zr[n][k];
        acc.x += wv.x * zv.x; acc.y += wv.y * zv.y;
        acc.z += wv.z * zv.z; acc.w += wv.w * zv.w;
    }
    float s = (acc.x + acc.y) + (acc.z + acc.w);
    zio[(size_t)node * F_H + f] = s * dinv[node];
}

// ---------------------------------------------------------------------------
// Aggregate L2 + head: out = dot(dinv*agg + b2, Wc) + bc
// ---------------------------------------------------------------------------
__global__ void k_agg2_head(const int* __restrict__ row_ptr, const int* __restrict__ srcs,
                            const float* __restrict__ hs2, const float* __restrict__ dinv,
                            const float* __restrict__ b2, const float* __restrict__ Wc,
                            const float* __restrict__ bc, float* __restrict__ out) {
    unsigned tid = blockIdx.x * blockDim.x + threadIdx.x;
    unsigned node = tid >> 6;
    int f = tid & 63;
    if (node >= N_NODES) return;
    int beg = row_ptr[node], end = row_ptr[node + 1];
    float v = hs2[(size_t)node * F_H + f];
    int j = beg;
    for (; j + 4 <= end; j += 4) {
        int s0 = srcs[j], s1 = srcs[j + 1], s2 = srcs[j + 2], s3 = srcs[j + 3];
        float a = hs2[(size_t)s0 * F_H + f];
        float b = hs2[(size_t)s1 * F_H + f];
        float c = hs2[(size_t)s2 * F_H + f];
        float d = hs2[(size_t)s3 * F_H + f];
        v += (a + b) + (c + d);
    }
    for (; j < end; j++) v += hs2[(size_t)srcs[j] * F_H + f];
    float r = (dinv[node] * v + b2[f]) * Wc[f];
#pragma unroll
    for (int off = 32; off > 0; off >>= 1)
        r += __shfl_xor(r, off, 64);
    if (f == 0) out[node] = r + bc[0];
}

// ---------------------------------------------------------------------------
extern "C" void kernel_launch(void* const* d_in, const int* in_sizes, int n_in,
                              void* d_out, int out_size, void* d_ws, size_t ws_size,
                              hipStream_t stream) {
    const float* x  = (const float*)d_in[0];
    const int*   ei = (const int*)d_in[1];
    const int*   src = ei;
    const int*   dst = ei + N_EDGES;
    const float* W1 = (const float*)d_in[2];
    const float* b1 = (const float*)d_in[3];
    const float* W2 = (const float*)d_in[4];
    const float* b2 = (const float*)d_in[5];
    const float* Wc = (const float*)d_in[6];
    const float* bc = (const float*)d_in[7];
    float* out = (float*)d_out;

    char* w = (char*)d_ws;
    int*   counts  = (int*)w;   w += (size_t)N_NODES * 4;
    int*   cursor  = (int*)w;   w += (size_t)N_NODES * 4;
    int*   row_ptr = (int*)w;   w += ((size_t)N_NODES + 4) * 4;
    float* dinv    = (float*)w; w += (size_t)N_NODES * 4;
    int*   partials= (int*)w;   w += 128 * 4;
    int*   bcur    = (int*)w;   w += NBUCK * 4;
    int*   srcs    = (int*)w;   w += (size_t)N_EDGES * 4;
    float* bufA    = (float*)w; w += (size_t)N_NODES * F_H * 4;
    float* bufB    = (float*)w; w += (size_t)N_NODES * F_H * 4;
    // during the sort, bufA/bufB are dead -> alias intermediate pair arrays
    int* srcT = (int*)bufA;
    int* dstT = (int*)bufB;

    const int TB = 256;
    const int NB_SC = (N_NODES + SC_CHUNK - 1) / SC_CHUNK;   // 100
    const int NB_PA = (int)(((long long)N_EDGES + PA_C - 1) / PA_C); // 782

    hipMemsetAsync(counts, 0, (size_t)N_NODES * 4, stream);
    k_hist <<<(N_EDGES + TB - 1) / TB, TB, 0, stream>>>(dst, counts);
    k_scan1<<<NB_SC, SC_T, 0, stream>>>(counts, row_ptr, partials);
    k_scan2<<<1, 128, 0, stream>>>(partials, row_ptr);
    k_scan3<<<NB_SC, SC_T, 0, stream>>>(counts, partials, row_ptr, cursor, dinv, bcur);
    k_partA<<<NB_PA, PA_T, 0, stream>>>(src, dst, bcur, srcT, dstT);
    k_partB<<<NBUCK, PB_T, 0, stream>>>(row_ptr, srcT, dstT, cursor, srcs);

    // layer 1
    k_gemm1<<<(N_NODES + G1_N - 1) / G1_N, G1_T, 0, stream>>>(x, W1, dinv, bufA);
    k_agg1<<<((unsigned)N_NODES * 64 + TB - 1) / TB, TB, 0, stream>>>(row_ptr, srcs, bufA, dinv, b1, bufB);

    // layer 2 (in place on bufB)
    k_gemm2<<<(N_NODES + G2_N - 1) / G2_N, G2_T, 0, stream>>>(W2, dinv, bufB);
    k_agg2_head<<<((unsigned)N_NODES * 64 + TB - 1) / TB, TB, 0, stream>>>(row_ptr, srcs, bufB, dinv, b2, Wc, bc, out);
}

// Round 4
// 649.360 us; speedup vs baseline: 2.6998x; 1.2880x over previous
//
#include <hip/hip_runtime.h>
#include <hip/hip_bf16.h>

#define N_NODES 100000
#define N_EDGES 3200000
#define F_IN    128
#define F_H     64

#define NBUCK 256
#define NPB   391            // ceil(N_NODES / NBUCK); last bucket short

// ---------------------------------------------------------------------------
// degree histogram
// ---------------------------------------------------------------------------
__global__ void k_hist(const int* __restrict__ dst, int* __restrict__ counts) {
    int e = blockIdx.x * blockDim.x + threadIdx.x;
    if (e < N_EDGES) atomicAdd(&counts[dst[e]], 1);
}

// ---------------------------------------------------------------------------
// 3-phase exclusive scan over counts[N] -> row_ptr, plus cursor/dinv/bucket bases
// ---------------------------------------------------------------------------
#define SC_CHUNK 1000
#define SC_T     1024
__global__ __launch_bounds__(SC_T) void k_scan1(const int* __restrict__ counts,
                                                int* __restrict__ row_ptr,
                                                int* __restrict__ partials) {
    __shared__ int s[SC_T];
    int t = threadIdx.x;
    int node = blockIdx.x * SC_CHUNK + t;
    int c = (t < SC_CHUNK) ? counts[node] : 0;
    s[t] = c;
    __syncthreads();
    for (int off = 1; off < SC_T; off <<= 1) {
        int v = (t >= off) ? s[t - off] : 0;
        __syncthreads();
        s[t] += v;
        __syncthreads();
    }
    if (t < SC_CHUNK) row_ptr[node] = s[t] - c;   // local exclusive
    if (t == SC_T - 1) partials[blockIdx.x] = s[t];
}

__global__ __launch_bounds__(128) void k_scan2(int* __restrict__ partials,
                                               int* __restrict__ row_ptr) {
    __shared__ int s[128];
    int t = threadIdx.x;
    const int NB = (N_NODES + SC_CHUNK - 1) / SC_CHUNK;   // 100
    int c = (t < NB) ? partials[t] : 0;
    s[t] = c;
    __syncthreads();
    for (int off = 1; off < 128; off <<= 1) {
        int v = (t >= off) ? s[t - off] : 0;
        __syncthreads();
        s[t] += v;
        __syncthreads();
    }
    if (t < NB) partials[t] = s[t] - c;           // exclusive base per block
    if (t == 127) row_ptr[N_NODES] = s[127];      // total = N_EDGES
}

__global__ __launch_bounds__(SC_T) void k_scan3(const int* __restrict__ counts,
                                                const int* __restrict__ partials,
                                                int* __restrict__ row_ptr,
                                                int* __restrict__ cursor,
                                                float* __restrict__ dinv,
                                                int* __restrict__ bucket_cursor) {
    int t = threadIdx.x;
    if (t >= SC_CHUNK) return;
    int node = blockIdx.x * SC_CHUNK + t;
    int r = row_ptr[node] + partials[blockIdx.x];
    row_ptr[node] = r;
    cursor[node]  = r;
    dinv[node] = rsqrtf((float)(counts[node] + 1));
    if (node % NPB == 0) bucket_cursor[node / NPB] = r;
}

// ---------------------------------------------------------------------------
// Pass A: partition edges into NBUCK dst-range buckets (LDS-staged, coalesced out)
// ---------------------------------------------------------------------------
#define PA_T   256
#define PA_C   4096
#define PA_PER (PA_C / PA_T)   // 16
__global__ __launch_bounds__(PA_T) void k_partA(const int* __restrict__ src,
                                                const int* __restrict__ dst,
                                                int* __restrict__ bucket_cursor,
                                                int* __restrict__ srcT,
                                                int* __restrict__ dstT) {
    __shared__ int lcount[NBUCK];
    __shared__ int lstart[NBUCK];
    __shared__ int loffs[NBUCK];
    __shared__ int lbase[NBUCK];
    __shared__ int s_src[PA_C];
    __shared__ int s_dst[PA_C];
    __shared__ unsigned char s_bkt[PA_C];
    __shared__ int ltot;
    int t = threadIdx.x;
    long long e0 = (long long)blockIdx.x * PA_C;
    if (t < NBUCK) lcount[t] = 0;
    __syncthreads();
    int es[PA_PER], ed[PA_PER];
    short eb[PA_PER];
#pragma unroll
    for (int i = 0; i < PA_PER; i++) {
        long long e = e0 + i * PA_T + t;
        if (e < N_EDGES) {
            es[i] = src[e]; ed[i] = dst[e];
            int b = ed[i] / NPB;
            eb[i] = (short)b;
            atomicAdd(&lcount[b], 1);
        } else eb[i] = -1;
    }
    __syncthreads();
    // exclusive scan of lcount (256) by wave 0: 4 serial/lane + shfl scan
    if (t < 64) {
        int base = t * 4;
        int c0 = lcount[base], c1 = lcount[base + 1], c2 = lcount[base + 2], c3 = lcount[base + 3];
        int ssum = c0 + c1 + c2 + c3;
        int sc = ssum;
#pragma unroll
        for (int off = 1; off < 64; off <<= 1) {
            int v = __shfl_up(sc, off, 64);
            if (t >= off) sc += v;
        }
        int ex = sc - ssum;
        lstart[base]     = ex;
        lstart[base + 1] = ex + c0;
        lstart[base + 2] = ex + c0 + c1;
        lstart[base + 3] = ex + c0 + c1 + c2;
        if (t == 63) ltot = sc;
    }
    __syncthreads();
    if (t < NBUCK) {
        loffs[t] = lstart[t];
        int c = lcount[t];
        lbase[t] = c ? atomicAdd(&bucket_cursor[t], c) : 0;
    }
    __syncthreads();
#pragma unroll
    for (int i = 0; i < PA_PER; i++) {
        if (eb[i] >= 0) {
            int idx = atomicAdd(&loffs[eb[i]], 1);
            s_src[idx] = es[i];
            s_dst[idx] = ed[i];
            s_bkt[idx] = (unsigned char)eb[i];
        }
    }
    __syncthreads();
    int tot = ltot;
    for (int i = t; i < tot; i += PA_T) {
        int b = s_bkt[i];
        int addr = lbase[b] + (i - lstart[b]);
        srcT[addr] = s_src[i];
        dstT[addr] = s_dst[i];
    }
}

// ---------------------------------------------------------------------------
// Pass B: per-bucket LDS counting sort -> final srcs[] segment (coalesced)
// ---------------------------------------------------------------------------
#define PB_T   1024
#define PB_CAP 16384
__global__ __launch_bounds__(PB_T) void k_partB(const int* __restrict__ row_ptr,
                                                const int* __restrict__ srcT,
                                                const int* __restrict__ dstT,
                                                int* __restrict__ cursor,
                                                int* __restrict__ srcs) {
    __shared__ int lhist[NPB];
    __shared__ int lcur[NPB];
    __shared__ int s_out[PB_CAP];
    int b = blockIdx.x;
    int node0 = b * NPB;
    int node1 = min(node0 + NPB, N_NODES);
    int beg = row_ptr[node0];
    int end = row_ptr[node1];
    int len = end - beg;
    int t = threadIdx.x;
    if (len <= PB_CAP) {
        for (int i = t; i < NPB; i += PB_T) lhist[i] = 0;
        __syncthreads();
        for (int i = t; i < len; i += PB_T)
            atomicAdd(&lhist[dstT[beg + i] - node0], 1);
        __syncthreads();
        if (t < 64) {   // exclusive scan of 391 counters: 7/lane + shfl
            int base = t * 7;
            int c[7]; int ssum = 0;
#pragma unroll
            for (int j = 0; j < 7; j++) {
                int idx = base + j;
                c[j] = (idx < NPB) ? lhist[idx] : 0;
                ssum += c[j];
            }
            int sc = ssum;
#pragma unroll
            for (int off = 1; off < 64; off <<= 1) {
                int v = __shfl_up(sc, off, 64);
                if (t >= off) sc += v;
            }
            int ex = sc - ssum;
#pragma unroll
            for (int j = 0; j < 7; j++) {
                int idx = base + j;
                if (idx < NPB) lcur[idx] = ex;
                ex += c[j];
            }
        }
        __syncthreads();
        for (int i = t; i < len; i += PB_T) {
            int d = dstT[beg + i] - node0;
            int sv = srcT[beg + i];
            int idx = atomicAdd(&lcur[d], 1);
            s_out[idx] = sv;
        }
        __syncthreads();
        for (int i = t; i < len; i += PB_T)
            srcs[beg + i] = s_out[i];
    } else {            // statistically never: safe fallback via global cursors
        for (int i = t; i < len; i += PB_T) {
            int d = dstT[beg + i];
            int pos = atomicAdd(&cursor[d], 1);
            srcs[pos] = srcT[beg + i];
        }
    }
}

// ---------------------------------------------------------------------------
// Layer-1 GEMM: hs = (x @ W1^T) * dinv
// Register-tiled: block = 256 thr (4 waves), 128 nodes/block.
// Wave tile 64f x 32n; lane(fi 0..15, ni 0..3) owns 4f x 8n accumulator.
// LDS k-major: wT[k][f] (stride 68), xT[k][n] (stride 128).
//   w-read:  b128 at 4*fi -> fi/fi+8 2-way (free), ni broadcast
//   x-read:  b128 at ni*8 -> pure broadcast, conflict-free
//   staging: lane-contiguous f / n -> conflict-free writes
// ---------------------------------------------------------------------------
#define GT   256
#define NTB  128     // nodes per block
#define KT   64      // k-tile (2 passes for F_IN=128)
#define WTS  68      // wT stride (words)

__global__ __launch_bounds__(GT) void k_gemm1(const float* __restrict__ x,
                                              const float* __restrict__ W1,
                                              const float* __restrict__ dinv,
                                              float* __restrict__ hs) {
    __shared__ float wT[KT * WTS];     // 17.4 KB
    __shared__ float xT[KT * NTB];     // 32 KB
    int t = threadIdx.x;
    int node0 = blockIdx.x * NTB;
    int lane = t & 63, wv = t >> 6;
    int fi = lane & 15, ni = lane >> 4;
    int n0 = wv * 32 + ni * 8;         // this lane's first node offset in block

    float acc[4][8];
#pragma unroll
    for (int r = 0; r < 4; r++)
#pragma unroll
        for (int c = 0; c < 8; c++) acc[r][c] = 0.0f;

    for (int p = 0; p < 2; p++) {
        int k0 = p * KT;
        if (p) __syncthreads();        // previous pass reads complete
        // stage W1 chunk (transposed)
        {
            int f = t & 63, kq = t >> 6;
            const float4* wp = (const float4*)&W1[(size_t)f * F_IN + k0 + kq * 16];
#pragma unroll
            for (int j = 0; j < 4; j++) {
                float4 v = wp[j];
                int kl = kq * 16 + 4 * j;
                wT[(kl + 0) * WTS + f] = v.x;
                wT[(kl + 1) * WTS + f] = v.y;
                wT[(kl + 2) * WTS + f] = v.z;
                wT[(kl + 3) * WTS + f] = v.w;
            }
        }
        // stage x chunk (transposed)
        {
            int n = t & 127, half = t >> 7;
            int node = node0 + n;
#pragma unroll
            for (int j = 0; j < 8; j++) {
                int ku = half * 8 + j;                 // 0..15
                float4 v = make_float4(0.f, 0.f, 0.f, 0.f);
                if (node < N_NODES)
                    v = *(const float4*)&x[(size_t)node * F_IN + k0 + 4 * ku];
                int kl = 4 * ku;
                xT[(kl + 0) * NTB + n] = v.x;
                xT[(kl + 1) * NTB + n] = v.y;
                xT[(kl + 2) * NTB + n] = v.z;
                xT[(kl + 3) * NTB + n] = v.w;
            }
        }
        __syncthreads();
#pragma unroll 8
        for (int k = 0; k < KT; k++) {
            float4 wf = *(const float4*)&wT[k * WTS + fi * 4];
            float4 xa = *(const float4*)&xT[k * NTB + n0];
            float4 xb = *(const float4*)&xT[k * NTB + n0 + 4];
            float wr[4] = {wf.x, wf.y, wf.z, wf.w};
            float xv[8] = {xa.x, xa.y, xa.z, xa.w, xb.x, xb.y, xb.z, xb.w};
#pragma unroll
            for (int r = 0; r < 4; r++)
#pragma unroll
                for (int c = 0; c < 8; c++) acc[r][c] += wr[r] * xv[c];
        }
    }
    // epilogue: coalesced float4 stores, scale by dinv
#pragma unroll
    for (int c = 0; c < 8; c++) {
        int node = node0 + n0 + c;
        if (node < N_NODES) {
            float dv = dinv[node];
            float4 o = make_float4(acc[0][c] * dv, acc[1][c] * dv,
                                   acc[2][c] * dv, acc[3][c] * dv);
            *(float4*)&hs[(size_t)node * F_H + fi * 4] = o;
        }
    }
}

// ---------------------------------------------------------------------------
// Layer-2 GEMM (out-of-place): hs2 = (z @ W2^T) * dinv ; same tiling, K=64
// ---------------------------------------------------------------------------
__global__ __launch_bounds__(GT) void k_gemm2(const float* __restrict__ z,
                                              const float* __restrict__ W2,
                                              const float* __restrict__ dinv,
                                              float* __restrict__ hs2) {
    __shared__ float wT[KT * WTS];
    __shared__ float zT[KT * NTB];
    int t = threadIdx.x;
    int node0 = blockIdx.x * NTB;
    int lane = t & 63, wv = t >> 6;
    int fi = lane & 15, ni = lane >> 4;
    int n0 = wv * 32 + ni * 8;

    // stage W2 (transposed): 64x64
    {
        int f = t & 63, kq = t >> 6;
        const float4* wp = (const float4*)&W2[(size_t)f * F_H + kq * 16];
#pragma unroll
        for (int j = 0; j < 4; j++) {
            float4 v = wp[j];
            int kl = kq * 16 + 4 * j;
            wT[(kl + 0) * WTS + f] = v.x;
            wT[(kl + 1) * WTS + f] = v.y;
            wT[(kl + 2) * WTS + f] = v.z;
            wT[(kl + 3) * WTS + f] = v.w;
        }
    }
    // stage z (transposed)
    {
        int n = t & 127, half = t >> 7;
        int node = node0 + n;
#pragma unroll
        for (int j = 0; j < 8; j++) {
            int ku = half * 8 + j;
            float4 v = make_float4(0.f, 0.f, 0.f, 0.f);
            if (node < N_NODES)
                v = *(const float4*)&z[(size_t)node * F_H + 4 * ku];
            int kl = 4 * ku;
            zT[(kl + 0) * NTB + n] = v.x;
            zT[(kl + 1) * NTB + n] = v.y;
            zT[(kl + 2) * NTB + n] = v.z;
            zT[(kl + 3) * NTB + n] = v.w;
        }
    }
    __syncthreads();
    float acc[4][8];
#pragma unroll
    for (int r = 0; r < 4; r++)
#pragma unroll
        for (int c = 0; c < 8; c++) acc[r][c] = 0.0f;
#pragma unroll 8
    for (int k = 0; k < KT; k++) {
        float4 wf = *(const float4*)&wT[k * WTS + fi * 4];
        float4 xa = *(const float4*)&zT[k * NTB + n0];
        float4 xb = *(const float4*)&zT[k * NTB + n0 + 4];
        float wr[4] = {wf.x, wf.y, wf.z, wf.w};
        float xv[8] = {xa.x, xa.y, xa.z, xa.w, xb.x, xb.y, xb.z, xb.w};
#pragma unroll
        for (int r = 0; r < 4; r++)
#pragma unroll
            for (int c = 0; c < 8; c++) acc[r][c] += wr[r] * xv[c];
    }
#pragma unroll
    for (int c = 0; c < 8; c++) {
        int node = node0 + n0 + c;
        if (node < N_NODES) {
            float dv = dinv[node];
            float4 o = make_float4(acc[0][c] * dv, acc[1][c] * dv,
                                   acc[2][c] * dv, acc[3][c] * dv);
            *(float4*)&hs2[(size_t)node * F_H + fi * 4] = o;
        }
    }
}

// ---------------------------------------------------------------------------
// Aggregate L1 + epilogue: z = relu(dinv * (self + sum_neighbors) + b1)
// one wave per node, lane = feature, 8-deep gather unroll
// ---------------------------------------------------------------------------
__global__ void k_agg1(const int* __restrict__ row_ptr, const int* __restrict__ srcs,
                       const float* __restrict__ hs, const float* __restrict__ dinv,
                       const float* __restrict__ b1, float* __restrict__ z) {
    unsigned tid = blockIdx.x * blockDim.x + threadIdx.x;
    unsigned node = tid >> 6;
    int f = tid & 63;
    if (node >= N_NODES) return;
    int beg = row_ptr[node], end = row_ptr[node + 1];
    float v = hs[(size_t)node * F_H + f];
    int j = beg;
    for (; j + 8 <= end; j += 8) {
        int s0 = srcs[j],     s1 = srcs[j + 1], s2 = srcs[j + 2], s3 = srcs[j + 3];
        int s4 = srcs[j + 4], s5 = srcs[j + 5], s6 = srcs[j + 6], s7 = srcs[j + 7];
        float a0 = hs[(size_t)s0 * F_H + f];
        float a1 = hs[(size_t)s1 * F_H + f];
        float a2 = hs[(size_t)s2 * F_H + f];
        float a3 = hs[(size_t)s3 * F_H + f];
        float a4 = hs[(size_t)s4 * F_H + f];
        float a5 = hs[(size_t)s5 * F_H + f];
        float a6 = hs[(size_t)s6 * F_H + f];
        float a7 = hs[(size_t)s7 * F_H + f];
        v += ((a0 + a1) + (a2 + a3)) + ((a4 + a5) + (a6 + a7));
    }
    for (; j < end; j++) v += hs[(size_t)srcs[j] * F_H + f];
    z[(size_t)node * F_H + f] = fmaxf(dinv[node] * v + b1[f], 0.0f);
}

// ---------------------------------------------------------------------------
// Aggregate L2 + head: out = dot(dinv*agg + b2, Wc) + bc
// ---------------------------------------------------------------------------
__global__ void k_agg2_head(const int* __restrict__ row_ptr, const int* __restrict__ srcs,
                            const float* __restrict__ hs2, const float* __restrict__ dinv,
                            const float* __restrict__ b2, const float* __restrict__ Wc,
                            const float* __restrict__ bc, float* __restrict__ out) {
    unsigned tid = blockIdx.x * blockDim.x + threadIdx.x;
    unsigned node = tid >> 6;
    int f = tid & 63;
    if (node >= N_NODES) return;
    int beg = row_ptr[node], end = row_ptr[node + 1];
    float v = hs2[(size_t)node * F_H + f];
    int j = beg;
    for (; j + 8 <= end; j += 8) {
        int s0 = srcs[j],     s1 = srcs[j + 1], s2 = srcs[j + 2], s3 = srcs[j + 3];
        int s4 = srcs[j + 4], s5 = srcs[j + 5], s6 = srcs[j + 6], s7 = srcs[j + 7];
        float a0 = hs2[(size_t)s0 * F_H + f];
        float a1 = hs2[(size_t)s1 * F_H + f];
        float a2 = hs2[(size_t)s2 * F_H + f];
        float a3 = hs2[(size_t)s3 * F_H + f];
        float a4 = hs2[(size_t)s4 * F_H + f];
        float a5 = hs2[(size_t)s5 * F_H + f];
        float a6 = hs2[(size_t)s6 * F_H + f];
        float a7 = hs2[(size_t)s7 * F_H + f];
        v += ((a0 + a1) + (a2 + a3)) + ((a4 + a5) + (a6 + a7));
    }
    for (; j < end; j++) v += hs2[(size_t)srcs[j] * F_H + f];
    float r = (dinv[node] * v + b2[f]) * Wc[f];
#pragma unroll
    for (int off = 32; off > 0; off >>= 1)
        r += __shfl_xor(r, off, 64);
    if (f == 0) out[node] = r + bc[0];
}

// ---------------------------------------------------------------------------
extern "C" void kernel_launch(void* const* d_in, const int* in_sizes, int n_in,
                              void* d_out, int out_size, void* d_ws, size_t ws_size,
                              hipStream_t stream) {
    const float* x  = (const float*)d_in[0];
    const int*   ei = (const int*)d_in[1];
    const int*   src = ei;
    const int*   dst = ei + N_EDGES;
    const float* W1 = (const float*)d_in[2];
    const float* b1 = (const float*)d_in[3];
    const float* W2 = (const float*)d_in[4];
    const float* b2 = (const float*)d_in[5];
    const float* Wc = (const float*)d_in[6];
    const float* bc = (const float*)d_in[7];
    float* out = (float*)d_out;

    char* w = (char*)d_ws;
    int*   counts  = (int*)w;   w += (size_t)N_NODES * 4;
    int*   cursor  = (int*)w;   w += (size_t)N_NODES * 4;
    int*   row_ptr = (int*)w;   w += ((size_t)N_NODES + 4) * 4;
    float* dinv    = (float*)w; w += (size_t)N_NODES * 4;
    int*   partials= (int*)w;   w += 128 * 4;
    int*   bcur    = (int*)w;   w += NBUCK * 4;
    int*   srcs    = (int*)w;   w += (size_t)N_EDGES * 4;
    float* bufA    = (float*)w; w += (size_t)N_NODES * F_H * 4;  // hs1 / hs2
    float* bufB    = (float*)w; w += (size_t)N_NODES * F_H * 4;  // z
    // during the sort, bufA/bufB are dead -> alias intermediate pair arrays
    int* srcT = (int*)bufA;
    int* dstT = (int*)bufB;

    const int TB = 256;
    const int NB_SC = (N_NODES + SC_CHUNK - 1) / SC_CHUNK;            // 100
    const int NB_PA = (int)(((long long)N_EDGES + PA_C - 1) / PA_C);  // 782
    const int NB_G  = (N_NODES + NTB - 1) / NTB;                      // 782

    hipMemsetAsync(counts, 0, (size_t)N_NODES * 4, stream);
    k_hist <<<(N_EDGES + TB - 1) / TB, TB, 0, stream>>>(dst, counts);
    k_scan1<<<NB_SC, SC_T, 0, stream>>>(counts, row_ptr, partials);
    k_scan2<<<1, 128, 0, stream>>>(partials, row_ptr);
    k_scan3<<<NB_SC, SC_T, 0, stream>>>(counts, partials, row_ptr, cursor, dinv, bcur);
    k_partA<<<NB_PA, PA_T, 0, stream>>>(src, dst, bcur, srcT, dstT);
    k_partB<<<NBUCK, PB_T, 0, stream>>>(row_ptr, srcT, dstT, cursor, srcs);

    // layer 1: gemm -> bufA(hs1), aggregate -> bufB(z)
    k_gemm1<<<NB_G, GT, 0, stream>>>(x, W1, dinv, bufA);
    k_agg1<<<((unsigned)N_NODES * 64 + TB - 1) / TB, TB, 0, stream>>>(row_ptr, srcs, bufA, dinv, b1, bufB);

    // layer 2: gemm bufB -> bufA(hs2), aggregate+head -> out
    k_gemm2<<<NB_G, GT, 0, stream>>>(bufB, W2, dinv, bufA);
    k_agg2_head<<<((unsigned)N_NODES * 64 + TB - 1) / TB, TB, 0, stream>>>(row_ptr, srcs, bufA, dinv, b2, Wc, bc, out);
}

// Round 5
// 538.624 us; speedup vs baseline: 3.2548x; 1.2056x over previous
//
#include <hip/hip_runtime.h>
#include <hip/hip_bf16.h>
#include <hip/hip_fp16.h>

#define N_NODES 100000
#define N_EDGES 3200000
#define F_IN    128
#define F_H     64

#define NBUCK 256
#define NPB   391            // ceil(N_NODES / NBUCK); last bucket short
#define SRC_BITS 17          // N_NODES < 2^17; pack = (dstLocal<<17)|src

// ---------------------------------------------------------------------------
// degree histogram
// ---------------------------------------------------------------------------
__global__ void k_hist(const int* __restrict__ dst, int* __restrict__ counts) {
    int e = blockIdx.x * blockDim.x + threadIdx.x;
    if (e < N_EDGES) atomicAdd(&counts[dst[e]], 1);
}

// ---------------------------------------------------------------------------
// 3-phase exclusive scan over counts[N] -> row_ptr, plus cursor/dinv/bucket bases
// ---------------------------------------------------------------------------
#define SC_CHUNK 1000
#define SC_T     1024
__global__ __launch_bounds__(SC_T) void k_scan1(const int* __restrict__ counts,
                                                int* __restrict__ row_ptr,
                                                int* __restrict__ partials) {
    __shared__ int s[SC_T];
    int t = threadIdx.x;
    int node = blockIdx.x * SC_CHUNK + t;
    int c = (t < SC_CHUNK) ? counts[node] : 0;
    s[t] = c;
    __syncthreads();
    for (int off = 1; off < SC_T; off <<= 1) {
        int v = (t >= off) ? s[t - off] : 0;
        __syncthreads();
        s[t] += v;
        __syncthreads();
    }
    if (t < SC_CHUNK) row_ptr[node] = s[t] - c;   // local exclusive
    if (t == SC_T - 1) partials[blockIdx.x] = s[t];
}

__global__ __launch_bounds__(128) void k_scan2(int* __restrict__ partials,
                                               int* __restrict__ row_ptr) {
    __shared__ int s[128];
    int t = threadIdx.x;
    const int NB = (N_NODES + SC_CHUNK - 1) / SC_CHUNK;   // 100
    int c = (t < NB) ? partials[t] : 0;
    s[t] = c;
    __syncthreads();
    for (int off = 1; off < 128; off <<= 1) {
        int v = (t >= off) ? s[t - off] : 0;
        __syncthreads();
        s[t] += v;
        __syncthreads();
    }
    if (t < NB) partials[t] = s[t] - c;           // exclusive base per block
    if (t == 127) row_ptr[N_NODES] = s[127];      // total = N_EDGES
}

__global__ __launch_bounds__(SC_T) void k_scan3(const int* __restrict__ counts,
                                                const int* __restrict__ partials,
                                                int* __restrict__ row_ptr,
                                                int* __restrict__ cursor,
                                                float* __restrict__ dinv,
                                                int* __restrict__ bucket_cursor) {
    int t = threadIdx.x;
    if (t >= SC_CHUNK) return;
    int node = blockIdx.x * SC_CHUNK + t;
    int r = row_ptr[node] + partials[blockIdx.x];
    row_ptr[node] = r;
    cursor[node]  = r;
    dinv[node] = rsqrtf((float)(counts[node] + 1));
    if (node % NPB == 0) bucket_cursor[node / NPB] = r;
}

// ---------------------------------------------------------------------------
// Pass A: partition edges into NBUCK dst-range buckets; emit packed
// (dstLocal<<17)|src words (LDS-staged, coalesced out)
// ---------------------------------------------------------------------------
#define PA_T   256
#define PA_C   4096
#define PA_PER (PA_C / PA_T)   // 16
__global__ __launch_bounds__(PA_T) void k_partA(const int* __restrict__ src,
                                                const int* __restrict__ dst,
                                                int* __restrict__ bucket_cursor,
                                                int* __restrict__ packT) {
    __shared__ int lcount[NBUCK];
    __shared__ int lstart[NBUCK];
    __shared__ int loffs[NBUCK];
    __shared__ int lbase[NBUCK];
    __shared__ int s_pack[PA_C];
    __shared__ unsigned char s_bkt[PA_C];
    __shared__ int ltot;
    int t = threadIdx.x;
    long long e0 = (long long)blockIdx.x * PA_C;
    if (t < NBUCK) lcount[t] = 0;
    __syncthreads();
    int ep[PA_PER];
    short eb[PA_PER];
#pragma unroll
    for (int i = 0; i < PA_PER; i++) {
        long long e = e0 + i * PA_T + t;
        if (e < N_EDGES) {
            int es = src[e], ed = dst[e];
            int b = ed / NPB;
            eb[i] = (short)b;
            ep[i] = ((ed - b * NPB) << SRC_BITS) | es;
            atomicAdd(&lcount[b], 1);
        } else eb[i] = -1;
    }
    __syncthreads();
    // exclusive scan of lcount (256) by wave 0: 4 serial/lane + shfl scan
    if (t < 64) {
        int base = t * 4;
        int c0 = lcount[base], c1 = lcount[base + 1], c2 = lcount[base + 2], c3 = lcount[base + 3];
        int ssum = c0 + c1 + c2 + c3;
        int sc = ssum;
#pragma unroll
        for (int off = 1; off < 64; off <<= 1) {
            int v = __shfl_up(sc, off, 64);
            if (t >= off) sc += v;
        }
        int ex = sc - ssum;
        lstart[base]     = ex;
        lstart[base + 1] = ex + c0;
        lstart[base + 2] = ex + c0 + c1;
        lstart[base + 3] = ex + c0 + c1 + c2;
        if (t == 63) ltot = sc;
    }
    __syncthreads();
    if (t < NBUCK) {
        loffs[t] = lstart[t];
        int c = lcount[t];
        lbase[t] = c ? atomicAdd(&bucket_cursor[t], c) : 0;
    }
    __syncthreads();
#pragma unroll
    for (int i = 0; i < PA_PER; i++) {
        if (eb[i] >= 0) {
            int idx = atomicAdd(&loffs[eb[i]], 1);
            s_pack[idx] = ep[i];
            s_bkt[idx] = (unsigned char)eb[i];
        }
    }
    __syncthreads();
    int tot = ltot;
    for (int i = t; i < tot; i += PA_T) {
        int b = s_bkt[i];
        int addr = lbase[b] + (i - lstart[b]);
        packT[addr] = s_pack[i];
    }
}

// ---------------------------------------------------------------------------
// Pass B: per-bucket LDS counting sort of packed words -> final srcs[] segment
// ---------------------------------------------------------------------------
#define PB_T   1024
#define PB_CAP 16384
__global__ __launch_bounds__(PB_T) void k_partB(const int* __restrict__ row_ptr,
                                                const int* __restrict__ packT,
                                                int* __restrict__ cursor,
                                                int* __restrict__ srcs) {
    __shared__ int lhist[NPB];
    __shared__ int lcur[NPB];
    __shared__ int s_out[PB_CAP];
    int b = blockIdx.x;
    int node0 = b * NPB;
    int node1 = min(node0 + NPB, N_NODES);
    int beg = row_ptr[node0];
    int end = row_ptr[node1];
    int len = end - beg;
    int t = threadIdx.x;
    const int SMASK = (1 << SRC_BITS) - 1;
    if (len <= PB_CAP) {
        for (int i = t; i < NPB; i += PB_T) lhist[i] = 0;
        __syncthreads();
        for (int i = t; i < len; i += PB_T)
            atomicAdd(&lhist[packT[beg + i] >> SRC_BITS], 1);
        __syncthreads();
        if (t < 64) {   // exclusive scan of 391 counters: 7/lane + shfl
            int base = t * 7;
            int c[7]; int ssum = 0;
#pragma unroll
            for (int j = 0; j < 7; j++) {
                int idx = base + j;
                c[j] = (idx < NPB) ? lhist[idx] : 0;
                ssum += c[j];
            }
            int sc = ssum;
#pragma unroll
            for (int off = 1; off < 64; off <<= 1) {
                int v = __shfl_up(sc, off, 64);
                if (t >= off) sc += v;
            }
            int ex = sc - ssum;
#pragma unroll
            for (int j = 0; j < 7; j++) {
                int idx = base + j;
                if (idx < NPB) lcur[idx] = ex;
                ex += c[j];
            }
        }
        __syncthreads();
        for (int i = t; i < len; i += PB_T) {
            int pk = packT[beg + i];
            int idx = atomicAdd(&lcur[pk >> SRC_BITS], 1);
            s_out[idx] = pk & SMASK;
        }
        __syncthreads();
        for (int i = t; i < len; i += PB_T)
            srcs[beg + i] = s_out[i];
    } else {            // statistically never: safe fallback via global cursors
        for (int i = t; i < len; i += PB_T) {
            int pk = packT[beg + i];
            int node = node0 + (pk >> SRC_BITS);
            int pos = atomicAdd(&cursor[node], 1);
            srcs[pos] = pk & SMASK;
        }
    }
}

// ---------------------------------------------------------------------------
// Layer-1 GEMM: hs16 = fp16( (x @ W1^T) * dinv )
// Register-tiled: block = 256 thr (4 waves), 128 nodes/block.
// Wave tile 64f x 32n; lane(fi 0..15, ni 0..3) owns 4f x 8n accumulator.
// LDS k-major: wT[k][f] (stride 68), xT[k][n] (stride 128) -> conflict-free.
// ---------------------------------------------------------------------------
#define GT   256
#define NTB  128     // nodes per block
#define KT   64      // k-tile (2 passes for F_IN=128)
#define WTS  68      // wT stride (words)

__global__ __launch_bounds__(GT) void k_gemm1(const float* __restrict__ x,
                                              const float* __restrict__ W1,
                                              const float* __restrict__ dinv,
                                              __half* __restrict__ hs) {
    __shared__ float wT[KT * WTS];     // 17.4 KB
    __shared__ float xT[KT * NTB];     // 32 KB
    int t = threadIdx.x;
    int node0 = blockIdx.x * NTB;
    int lane = t & 63, wv = t >> 6;
    int fi = lane & 15, ni = lane >> 4;
    int n0 = wv * 32 + ni * 8;         // this lane's first node offset in block

    float acc[4][8];
#pragma unroll
    for (int r = 0; r < 4; r++)
#pragma unroll
        for (int c = 0; c < 8; c++) acc[r][c] = 0.0f;

    for (int p = 0; p < 2; p++) {
        int k0 = p * KT;
        if (p) __syncthreads();        // previous pass reads complete
        // stage W1 chunk (transposed)
        {
            int f = t & 63, kq = t >> 6;
            const float4* wp = (const float4*)&W1[(size_t)f * F_IN + k0 + kq * 16];
#pragma unroll
            for (int j = 0; j < 4; j++) {
                float4 v = wp[j];
                int kl = kq * 16 + 4 * j;
                wT[(kl + 0) * WTS + f] = v.x;
                wT[(kl + 1) * WTS + f] = v.y;
                wT[(kl + 2) * WTS + f] = v.z;
                wT[(kl + 3) * WTS + f] = v.w;
            }
        }
        // stage x chunk (transposed)
        {
            int n = t & 127, half = t >> 7;
            int node = node0 + n;
#pragma unroll
            for (int j = 0; j < 8; j++) {
                int ku = half * 8 + j;                 // 0..15
                float4 v = make_float4(0.f, 0.f, 0.f, 0.f);
                if (node < N_NODES)
                    v = *(const float4*)&x[(size_t)node * F_IN + k0 + 4 * ku];
                int kl = 4 * ku;
                xT[(kl + 0) * NTB + n] = v.x;
                xT[(kl + 1) * NTB + n] = v.y;
                xT[(kl + 2) * NTB + n] = v.z;
                xT[(kl + 3) * NTB + n] = v.w;
            }
        }
        __syncthreads();
#pragma unroll 8
        for (int k = 0; k < KT; k++) {
            float4 wf = *(const float4*)&wT[k * WTS + fi * 4];
            float4 xa = *(const float4*)&xT[k * NTB + n0];
            float4 xb = *(const float4*)&xT[k * NTB + n0 + 4];
            float wr[4] = {wf.x, wf.y, wf.z, wf.w};
            float xv[8] = {xa.x, xa.y, xa.z, xa.w, xb.x, xb.y, xb.z, xb.w};
#pragma unroll
            for (int r = 0; r < 4; r++)
#pragma unroll
                for (int c = 0; c < 8; c++) acc[r][c] += wr[r] * xv[c];
        }
    }
    // epilogue: scale by dinv, fp16 pack, 8 B stores
#pragma unroll
    for (int c = 0; c < 8; c++) {
        int node = node0 + n0 + c;
        if (node < N_NODES) {
            float dv = dinv[node];
            __half2 h0 = __floats2half2_rn(acc[0][c] * dv, acc[1][c] * dv);
            __half2 h1 = __floats2half2_rn(acc[2][c] * dv, acc[3][c] * dv);
            __half2* p = (__half2*)&hs[(size_t)node * F_H + fi * 4];
            p[0] = h0; p[1] = h1;
        }
    }
}

// ---------------------------------------------------------------------------
// Layer-2 GEMM (out-of-place): hs2 = fp16( (z @ W2^T) * dinv ); z is fp16
// ---------------------------------------------------------------------------
__global__ __launch_bounds__(GT) void k_gemm2(const __half* __restrict__ z,
                                              const float* __restrict__ W2,
                                              const float* __restrict__ dinv,
                                              __half* __restrict__ hs2) {
    __shared__ float wT[KT * WTS];
    __shared__ float zT[KT * NTB];
    int t = threadIdx.x;
    int node0 = blockIdx.x * NTB;
    int lane = t & 63, wv = t >> 6;
    int fi = lane & 15, ni = lane >> 4;
    int n0 = wv * 32 + ni * 8;

    // stage W2 (transposed): 64x64
    {
        int f = t & 63, kq = t >> 6;
        const float4* wp = (const float4*)&W2[(size_t)f * F_H + kq * 16];
#pragma unroll
        for (int j = 0; j < 4; j++) {
            float4 v = wp[j];
            int kl = kq * 16 + 4 * j;
            wT[(kl + 0) * WTS + f] = v.x;
            wT[(kl + 1) * WTS + f] = v.y;
            wT[(kl + 2) * WTS + f] = v.z;
            wT[(kl + 3) * WTS + f] = v.w;
        }
    }
    // stage z (fp16 -> f32, transposed)
    {
        int n = t & 127, g = t >> 7;
        int node = node0 + n;
#pragma unroll
        for (int j = 0; j < 16; j++) {
            int h2 = g + 2 * j;                       // 0..31
            float2 f2 = make_float2(0.f, 0.f);
            if (node < N_NODES) {
                __half2 v = *(const __half2*)&z[(size_t)node * F_H + 2 * h2];
                f2 = __half22float2(v);
            }
            zT[(2 * h2 + 0) * NTB + n] = f2.x;
            zT[(2 * h2 + 1) * NTB + n] = f2.y;
        }
    }
    __syncthreads();
    float acc[4][8];
#pragma unroll
    for (int r = 0; r < 4; r++)
#pragma unroll
        for (int c = 0; c < 8; c++) acc[r][c] = 0.0f;
#pragma unroll 8
    for (int k = 0; k < KT; k++) {
        float4 wf = *(const float4*)&wT[k * WTS + fi * 4];
        float4 xa = *(const float4*)&zT[k * NTB + n0];
        float4 xb = *(const float4*)&zT[k * NTB + n0 + 4];
        float wr[4] = {wf.x, wf.y, wf.z, wf.w};
        float xv[8] = {xa.x, xa.y, xa.z, xa.w, xb.x, xb.y, xb.z, xb.w};
#pragma unroll
        for (int r = 0; r < 4; r++)
#pragma unroll
            for (int c = 0; c < 8; c++) acc[r][c] += wr[r] * xv[c];
    }
#pragma unroll
    for (int c = 0; c < 8; c++) {
        int node = node0 + n0 + c;
        if (node < N_NODES) {
            float dv = dinv[node];
            __half2 h0 = __floats2half2_rn(acc[0][c] * dv, acc[1][c] * dv);
            __half2 h1 = __floats2half2_rn(acc[2][c] * dv, acc[3][c] * dv);
            __half2* p = (__half2*)&hs2[(size_t)node * F_H + fi * 4];
            p[0] = h0; p[1] = h1;
        }
    }
}

// ---------------------------------------------------------------------------
// Aggregate L1 + epilogue: z16 = fp16(relu(dinv * (self + sum) + b1))
// one wave per node, lane = feature, 8-deep fp16 gather unroll
// ---------------------------------------------------------------------------
__global__ void k_agg1(const int* __restrict__ row_ptr, const int* __restrict__ srcs,
                       const __half* __restrict__ hs, const float* __restrict__ dinv,
                       const float* __restrict__ b1, __half* __restrict__ z) {
    unsigned tid = blockIdx.x * blockDim.x + threadIdx.x;
    unsigned node = tid >> 6;
    int f = tid & 63;
    if (node >= N_NODES) return;
    int beg = row_ptr[node], end = row_ptr[node + 1];
    float v = __half2float(hs[(size_t)node * F_H + f]);
    int j = beg;
    for (; j + 8 <= end; j += 8) {
        int s0 = srcs[j],     s1 = srcs[j + 1], s2 = srcs[j + 2], s3 = srcs[j + 3];
        int s4 = srcs[j + 4], s5 = srcs[j + 5], s6 = srcs[j + 6], s7 = srcs[j + 7];
        float a0 = __half2float(hs[(size_t)s0 * F_H + f]);
        float a1 = __half2float(hs[(size_t)s1 * F_H + f]);
        float a2 = __half2float(hs[(size_t)s2 * F_H + f]);
        float a3 = __half2float(hs[(size_t)s3 * F_H + f]);
        float a4 = __half2float(hs[(size_t)s4 * F_H + f]);
        float a5 = __half2float(hs[(size_t)s5 * F_H + f]);
        float a6 = __half2float(hs[(size_t)s6 * F_H + f]);
        float a7 = __half2float(hs[(size_t)s7 * F_H + f]);
        v += ((a0 + a1) + (a2 + a3)) + ((a4 + a5) + (a6 + a7));
    }
    for (; j < end; j++) v += __half2float(hs[(size_t)srcs[j] * F_H + f]);
    z[(size_t)node * F_H + f] = __float2half_rn(fmaxf(dinv[node] * v + b1[f], 0.0f));
}

// ---------------------------------------------------------------------------
// Aggregate L2 + head: out = dot(dinv*agg + b2, Wc) + bc
// ---------------------------------------------------------------------------
__global__ void k_agg2_head(const int* __restrict__ row_ptr, const int* __restrict__ srcs,
                            const __half* __restrict__ hs2, const float* __restrict__ dinv,
                            const float* __restrict__ b2, const float* __restrict__ Wc,
                            const float* __restrict__ bc, float* __restrict__ out) {
    unsigned tid = blockIdx.x * blockDim.x + threadIdx.x;
    unsigned node = tid >> 6;
    int f = tid & 63;
    if (node >= N_NODES) return;
    int beg = row_ptr[node], end = row_ptr[node + 1];
    float v = __half2float(hs2[(size_t)node * F_H + f]);
    int j = beg;
    for (; j + 8 <= end; j += 8) {
        int s0 = srcs[j],     s1 = srcs[j + 1], s2 = srcs[j + 2], s3 = srcs[j + 3];
        int s4 = srcs[j + 4], s5 = srcs[j + 5], s6 = srcs[j + 6], s7 = srcs[j + 7];
        float a0 = __half2float(hs2[(size_t)s0 * F_H + f]);
        float a1 = __half2float(hs2[(size_t)s1 * F_H + f]);
        float a2 = __half2float(hs2[(size_t)s2 * F_H + f]);
        float a3 = __half2float(hs2[(size_t)s3 * F_H + f]);
        float a4 = __half2float(hs2[(size_t)s4 * F_H + f]);
        float a5 = __half2float(hs2[(size_t)s5 * F_H + f]);
        float a6 = __half2float(hs2[(size_t)s6 * F_H + f]);
        float a7 = __half2float(hs2[(size_t)s7 * F_H + f]);
        v += ((a0 + a1) + (a2 + a3)) + ((a4 + a5) + (a6 + a7));
    }
    for (; j < end; j++) v += __half2float(hs2[(size_t)srcs[j] * F_H + f]);
    float r = (dinv[node] * v + b2[f]) * Wc[f];
#pragma unroll
    for (int off = 32; off > 0; off >>= 1)
        r += __shfl_xor(r, off, 64);
    if (f == 0) out[node] = r + bc[0];
}

// ---------------------------------------------------------------------------
extern "C" void kernel_launch(void* const* d_in, const int* in_sizes, int n_in,
                              void* d_out, int out_size, void* d_ws, size_t ws_size,
                              hipStream_t stream) {
    const float* x  = (const float*)d_in[0];
    const int*   ei = (const int*)d_in[1];
    const int*   src = ei;
    const int*   dst = ei + N_EDGES;
    const float* W1 = (const float*)d_in[2];
    const float* b1 = (const float*)d_in[3];
    const float* W2 = (const float*)d_in[4];
    const float* b2 = (const float*)d_in[5];
    const float* Wc = (const float*)d_in[6];
    const float* bc = (const float*)d_in[7];
    float* out = (float*)d_out;

    char* w = (char*)d_ws;
    int*    counts  = (int*)w;    w += (size_t)N_NODES * 4;
    int*    cursor  = (int*)w;    w += (size_t)N_NODES * 4;
    int*    row_ptr = (int*)w;    w += ((size_t)N_NODES + 4) * 4;
    float*  dinv    = (float*)w;  w += (size_t)N_NODES * 4;
    int*    partials= (int*)w;    w += 128 * 4;
    int*    bcur    = (int*)w;    w += NBUCK * 4;
    int*    srcs    = (int*)w;    w += (size_t)N_EDGES * 4;
    __half* bufA    = (__half*)w; w += (size_t)N_NODES * F_H * 2;  // hs1 / hs2 (12.8 MB)
    __half* bufB    = (__half*)w; w += (size_t)N_NODES * F_H * 2;  // z       (12.8 MB)
    int*    packT   = (int*)w;    w += (size_t)N_EDGES * 4;        // sort intermediate

    const int TB = 256;
    const int NB_SC = (N_NODES + SC_CHUNK - 1) / SC_CHUNK;            // 100
    const int NB_PA = (int)(((long long)N_EDGES + PA_C - 1) / PA_C);  // 782
    const int NB_G  = (N_NODES + NTB - 1) / NTB;                      // 782

    hipMemsetAsync(counts, 0, (size_t)N_NODES * 4, stream);
    k_hist <<<(N_EDGES + TB - 1) / TB, TB, 0, stream>>>(dst, counts);
    k_scan1<<<NB_SC, SC_T, 0, stream>>>(counts, row_ptr, partials);
    k_scan2<<<1, 128, 0, stream>>>(partials, row_ptr);
    k_scan3<<<NB_SC, SC_T, 0, stream>>>(counts, partials, row_ptr, cursor, dinv, bcur);
    k_partA<<<NB_PA, PA_T, 0, stream>>>(src, dst, bcur, packT);
    k_partB<<<NBUCK, PB_T, 0, stream>>>(row_ptr, packT, cursor, srcs);

    // layer 1: gemm -> bufA(hs1 fp16), aggregate -> bufB(z fp16)
    k_gemm1<<<NB_G, GT, 0, stream>>>(x, W1, dinv, bufA);
    k_agg1<<<((unsigned)N_NODES * 64 + TB - 1) / TB, TB, 0, stream>>>(row_ptr, srcs, bufA, dinv, b1, bufB);

    // layer 2: gemm bufB -> bufA(hs2 fp16), aggregate+head -> out
    k_gemm2<<<NB_G, GT, 0, stream>>>(bufB, W2, dinv, bufA);
    k_agg2_head<<<((unsigned)N_NODES * 64 + TB - 1) / TB, TB, 0, stream>>>(row_ptr, srcs, bufA, dinv, b2, Wc, bc, out);
}

// Round 6
// 428.927 us; speedup vs baseline: 4.0872x; 1.2557x over previous
//
#include <hip/hip_runtime.h>
#include <hip/hip_bf16.h>
#include <hip/hip_fp16.h>

#define N_NODES 100000
#define N_EDGES 3200000
#define F_IN    128
#define F_H     64

#define NBUCK 256
#define NPB   391            // ceil(N_NODES / NBUCK); last bucket short
#define SRC_BITS 17          // N_NODES < 2^17; pack = (dstLocal<<17)|src

// ---------------------------------------------------------------------------
// Bucket-level histogram: 256 bins, LDS-aggregated (50K global atomics total)
// ---------------------------------------------------------------------------
#define BH_T 256
#define BH_C 16384           // edges per block -> 196 blocks
__global__ __launch_bounds__(BH_T) void k_bhist(const int* __restrict__ dst,
                                                int* __restrict__ bcount) {
    __shared__ int lc[NBUCK];
    int t = threadIdx.x;
    lc[t] = 0;
    __syncthreads();
    long long e0 = (long long)blockIdx.x * BH_C;
    long long e1 = e0 + BH_C; if (e1 > N_EDGES) e1 = N_EDGES;
    for (long long e = e0 + t; e < e1; e += BH_T)
        atomicAdd(&lc[dst[e] / NPB], 1);
    __syncthreads();
    int c = lc[t];
    if (c) atomicAdd(&bcount[t], c);
}

// ---------------------------------------------------------------------------
// Scan of 256 bucket counts -> bucket bases + partA cursors; row_ptr[N]=E
// ---------------------------------------------------------------------------
__global__ __launch_bounds__(NBUCK) void k_bscan(const int* __restrict__ bcount,
                                                 int* __restrict__ bbase,
                                                 int* __restrict__ bcur,
                                                 int* __restrict__ row_ptr) {
    __shared__ int s[NBUCK];
    int t = threadIdx.x;
    int c = bcount[t];
    s[t] = c;
    __syncthreads();
    for (int off = 1; off < NBUCK; off <<= 1) {
        int v = (t >= off) ? s[t - off] : 0;
        __syncthreads();
        s[t] += v;
        __syncthreads();
    }
    int ex = s[t] - c;
    bbase[t] = ex;
    bcur[t]  = ex;
    if (t == NBUCK - 1) {
        bbase[NBUCK] = s[t];             // = N_EDGES
        row_ptr[N_NODES] = s[t];
    }
}

// ---------------------------------------------------------------------------
// Pass A: partition edges into NBUCK dst-range buckets; emit packed
// (dstLocal<<17)|src words (LDS-staged, coalesced out)
// ---------------------------------------------------------------------------
#define PA_T   256
#define PA_C   4096
#define PA_PER (PA_C / PA_T)   // 16
__global__ __launch_bounds__(PA_T) void k_partA(const int* __restrict__ src,
                                                const int* __restrict__ dst,
                                                int* __restrict__ bucket_cursor,
                                                int* __restrict__ packT) {
    __shared__ int lcount[NBUCK];
    __shared__ int lstart[NBUCK];
    __shared__ int loffs[NBUCK];
    __shared__ int lbase[NBUCK];
    __shared__ int s_pack[PA_C];
    __shared__ unsigned char s_bkt[PA_C];
    __shared__ int ltot;
    int t = threadIdx.x;
    long long e0 = (long long)blockIdx.x * PA_C;
    if (t < NBUCK) lcount[t] = 0;
    __syncthreads();
    int ep[PA_PER];
    short eb[PA_PER];
#pragma unroll
    for (int i = 0; i < PA_PER; i++) {
        long long e = e0 + i * PA_T + t;
        if (e < N_EDGES) {
            int es = src[e], ed = dst[e];
            int b = ed / NPB;
            eb[i] = (short)b;
            ep[i] = ((ed - b * NPB) << SRC_BITS) | es;
            atomicAdd(&lcount[b], 1);
        } else eb[i] = -1;
    }
    __syncthreads();
    // exclusive scan of lcount (256) by wave 0: 4 serial/lane + shfl scan
    if (t < 64) {
        int base = t * 4;
        int c0 = lcount[base], c1 = lcount[base + 1], c2 = lcount[base + 2], c3 = lcount[base + 3];
        int ssum = c0 + c1 + c2 + c3;
        int sc = ssum;
#pragma unroll
        for (int off = 1; off < 64; off <<= 1) {
            int v = __shfl_up(sc, off, 64);
            if (t >= off) sc += v;
        }
        int ex = sc - ssum;
        lstart[base]     = ex;
        lstart[base + 1] = ex + c0;
        lstart[base + 2] = ex + c0 + c1;
        lstart[base + 3] = ex + c0 + c1 + c2;
        if (t == 63) ltot = sc;
    }
    __syncthreads();
    if (t < NBUCK) {
        loffs[t] = lstart[t];
        int c = lcount[t];
        lbase[t] = c ? atomicAdd(&bucket_cursor[t], c) : 0;
    }
    __syncthreads();
#pragma unroll
    for (int i = 0; i < PA_PER; i++) {
        if (eb[i] >= 0) {
            int idx = atomicAdd(&loffs[eb[i]], 1);
            s_pack[idx] = ep[i];
            s_bkt[idx] = (unsigned char)eb[i];
        }
    }
    __syncthreads();
    int tot = ltot;
    for (int i = t; i < tot; i += PA_T) {
        int b = s_bkt[i];
        int addr = lbase[b] + (i - lstart[b]);
        packT[addr] = s_pack[i];
    }
}

// ---------------------------------------------------------------------------
// Pass B: per-bucket LDS counting sort of packed words -> srcs[] segment,
// plus derives row_ptr[node] and dinv[node] from the local histogram.
// ---------------------------------------------------------------------------
#define PB_T   1024
#define PB_CAP 16384
__global__ __launch_bounds__(PB_T) void k_partB(const int* __restrict__ bbase,
                                                const int* __restrict__ packT,
                                                int* __restrict__ row_ptr,
                                                float* __restrict__ dinv,
                                                int* __restrict__ srcs) {
    __shared__ int lhist[NPB];
    __shared__ int lcur[NPB];
    __shared__ int s_out[PB_CAP];
    int b = blockIdx.x;
    int node0 = b * NPB;
    int node1 = min(node0 + NPB, N_NODES);
    int nloc = node1 - node0;
    int beg = bbase[b];
    int end = bbase[b + 1];
    int len = end - beg;
    int t = threadIdx.x;
    const int SMASK = (1 << SRC_BITS) - 1;

    for (int i = t; i < NPB; i += PB_T) lhist[i] = 0;
    __syncthreads();
    for (int i = t; i < len; i += PB_T)
        atomicAdd(&lhist[packT[beg + i] >> SRC_BITS], 1);
    __syncthreads();
    if (t < 64) {   // exclusive scan of 391 counters: 7/lane + shfl
        int base = t * 7;
        int c[7]; int ssum = 0;
#pragma unroll
        for (int j = 0; j < 7; j++) {
            int idx = base + j;
            c[j] = (idx < NPB) ? lhist[idx] : 0;
            ssum += c[j];
        }
        int sc = ssum;
#pragma unroll
        for (int off = 1; off < 64; off <<= 1) {
            int v = __shfl_up(sc, off, 64);
            if (t >= off) sc += v;
        }
        int ex = sc - ssum;
#pragma unroll
        for (int j = 0; j < 7; j++) {
            int idx = base + j;
            if (idx < NPB) lcur[idx] = ex;
            ex += c[j];
        }
    }
    __syncthreads();
    // derive row_ptr / dinv from local exclusive prefix (before lcur mutates)
    for (int i = t; i < nloc; i += PB_T) {
        row_ptr[node0 + i] = beg + lcur[i];
        dinv[node0 + i] = rsqrtf((float)(lhist[i] + 1));
    }
    __syncthreads();
    if (len <= PB_CAP) {
        for (int i = t; i < len; i += PB_T) {
            int pk = packT[beg + i];
            int idx = atomicAdd(&lcur[pk >> SRC_BITS], 1);
            s_out[idx] = pk & SMASK;
        }
        __syncthreads();
        for (int i = t; i < len; i += PB_T)
            srcs[beg + i] = s_out[i];
    } else {    // statistically never (34 sigma): direct global scatter
        for (int i = t; i < len; i += PB_T) {
            int pk = packT[beg + i];
            int idx = atomicAdd(&lcur[pk >> SRC_BITS], 1);
            srcs[beg + idx] = pk & SMASK;
        }
    }
}

// ---------------------------------------------------------------------------
// Layer-1 GEMM: hs16 = fp16( (x @ W1^T) * dinv )
// Register-tiled: block = 256 thr (4 waves), 128 nodes/block.
// Wave tile 64f x 32n; lane(fi 0..15, ni 0..3) owns 4f x 8n accumulator.
// LDS k-major: wT[k][f] (stride 68), xT[k][n] (stride 128) -> conflict-free.
// ---------------------------------------------------------------------------
#define GT   256
#define NTB  128     // nodes per block
#define KT   64      // k-tile (2 passes for F_IN=128)
#define WTS  68      // wT stride (words)

__global__ __launch_bounds__(GT) void k_gemm1(const float* __restrict__ x,
                                              const float* __restrict__ W1,
                                              const float* __restrict__ dinv,
                                              __half* __restrict__ hs) {
    __shared__ float wT[KT * WTS];     // 17.4 KB
    __shared__ float xT[KT * NTB];     // 32 KB
    int t = threadIdx.x;
    int node0 = blockIdx.x * NTB;
    int lane = t & 63, wv = t >> 6;
    int fi = lane & 15, ni = lane >> 4;
    int n0 = wv * 32 + ni * 8;         // this lane's first node offset in block

    float acc[4][8];
#pragma unroll
    for (int r = 0; r < 4; r++)
#pragma unroll
        for (int c = 0; c < 8; c++) acc[r][c] = 0.0f;

    for (int p = 0; p < 2; p++) {
        int k0 = p * KT;
        if (p) __syncthreads();        // previous pass reads complete
        // stage W1 chunk (transposed)
        {
            int f = t & 63, kq = t >> 6;
            const float4* wp = (const float4*)&W1[(size_t)f * F_IN + k0 + kq * 16];
#pragma unroll
            for (int j = 0; j < 4; j++) {
                float4 v = wp[j];
                int kl = kq * 16 + 4 * j;
                wT[(kl + 0) * WTS + f] = v.x;
                wT[(kl + 1) * WTS + f] = v.y;
                wT[(kl + 2) * WTS + f] = v.z;
                wT[(kl + 3) * WTS + f] = v.w;
            }
        }
        // stage x chunk (transposed)
        {
            int n = t & 127, half = t >> 7;
            int node = node0 + n;
#pragma unroll
            for (int j = 0; j < 8; j++) {
                int ku = half * 8 + j;                 // 0..15
                float4 v = make_float4(0.f, 0.f, 0.f, 0.f);
                if (node < N_NODES)
                    v = *(const float4*)&x[(size_t)node * F_IN + k0 + 4 * ku];
                int kl = 4 * ku;
                xT[(kl + 0) * NTB + n] = v.x;
                xT[(kl + 1) * NTB + n] = v.y;
                xT[(kl + 2) * NTB + n] = v.z;
                xT[(kl + 3) * NTB + n] = v.w;
            }
        }
        __syncthreads();
#pragma unroll 8
        for (int k = 0; k < KT; k++) {
            float4 wf = *(const float4*)&wT[k * WTS + fi * 4];
            float4 xa = *(const float4*)&xT[k * NTB + n0];
            float4 xb = *(const float4*)&xT[k * NTB + n0 + 4];
            float wr[4] = {wf.x, wf.y, wf.z, wf.w};
            float xv[8] = {xa.x, xa.y, xa.z, xa.w, xb.x, xb.y, xb.z, xb.w};
#pragma unroll
            for (int r = 0; r < 4; r++)
#pragma unroll
                for (int c = 0; c < 8; c++) acc[r][c] += wr[r] * xv[c];
        }
    }
    // epilogue: scale by dinv, fp16 pack, 8 B stores
#pragma unroll
    for (int c = 0; c < 8; c++) {
        int node = node0 + n0 + c;
        if (node < N_NODES) {
            float dv = dinv[node];
            __half2 h0 = __floats2half2_rn(acc[0][c] * dv, acc[1][c] * dv);
            __half2 h1 = __floats2half2_rn(acc[2][c] * dv, acc[3][c] * dv);
            __half2* p = (__half2*)&hs[(size_t)node * F_H + fi * 4];
            p[0] = h0; p[1] = h1;
        }
    }
}

// ---------------------------------------------------------------------------
// Layer-2 GEMM (out-of-place): hs2 = fp16( (z @ W2^T) * dinv ); z is fp16
// ---------------------------------------------------------------------------
__global__ __launch_bounds__(GT) void k_gemm2(const __half* __restrict__ z,
                                              const float* __restrict__ W2,
                                              const float* __restrict__ dinv,
                                              __half* __restrict__ hs2) {
    __shared__ float wT[KT * WTS];
    __shared__ float zT[KT * NTB];
    int t = threadIdx.x;
    int node0 = blockIdx.x * NTB;
    int lane = t & 63, wv = t >> 6;
    int fi = lane & 15, ni = lane >> 4;
    int n0 = wv * 32 + ni * 8;

    // stage W2 (transposed): 64x64
    {
        int f = t & 63, kq = t >> 6;
        const float4* wp = (const float4*)&W2[(size_t)f * F_H + kq * 16];
#pragma unroll
        for (int j = 0; j < 4; j++) {
            float4 v = wp[j];
            int kl = kq * 16 + 4 * j;
            wT[(kl + 0) * WTS + f] = v.x;
            wT[(kl + 1) * WTS + f] = v.y;
            wT[(kl + 2) * WTS + f] = v.z;
            wT[(kl + 3) * WTS + f] = v.w;
        }
    }
    // stage z (fp16 -> f32, transposed)
    {
        int n = t & 127, g = t >> 7;
        int node = node0 + n;
#pragma unroll
        for (int j = 0; j < 16; j++) {
            int h2 = g + 2 * j;                       // 0..31
            float2 f2 = make_float2(0.f, 0.f);
            if (node < N_NODES) {
                __half2 v = *(const __half2*)&z[(size_t)node * F_H + 2 * h2];
                f2 = __half22float2(v);
            }
            zT[(2 * h2 + 0) * NTB + n] = f2.x;
            zT[(2 * h2 + 1) * NTB + n] = f2.y;
        }
    }
    __syncthreads();
    float acc[4][8];
#pragma unroll
    for (int r = 0; r < 4; r++)
#pragma unroll
        for (int c = 0; c < 8; c++) acc[r][c] = 0.0f;
#pragma unroll 8
    for (int k = 0; k < KT; k++) {
        float4 wf = *(const float4*)&wT[k * WTS + fi * 4];
        float4 xa = *(const float4*)&zT[k * NTB + n0];
        float4 xb = *(const float4*)&zT[k * NTB + n0 + 4];
        float wr[4] = {wf.x, wf.y, wf.z, wf.w};
        float xv[8] = {xa.x, xa.y, xa.z, xa.w, xb.x, xb.y, xb.z, xb.w};
#pragma unroll
        for (int r = 0; r < 4; r++)
#pragma unroll
            for (int c = 0; c < 8; c++) acc[r][c] += wr[r] * xv[c];
    }
#pragma unroll
    for (int c = 0; c < 8; c++) {
        int node = node0 + n0 + c;
        if (node < N_NODES) {
            float dv = dinv[node];
            __half2 h0 = __floats2half2_rn(acc[0][c] * dv, acc[1][c] * dv);
            __half2 h1 = __floats2half2_rn(acc[2][c] * dv, acc[3][c] * dv);
            __half2* p = (__half2*)&hs2[(size_t)node * F_H + fi * 4];
            p[0] = h0; p[1] = h1;
        }
    }
}

// ---------------------------------------------------------------------------
// Aggregate L1 + epilogue: z16 = fp16(relu(dinv * (self + sum) + b1))
// one wave per node, lane = feature, 8-deep fp16 gather unroll
// ---------------------------------------------------------------------------
__global__ void k_agg1(const int* __restrict__ row_ptr, const int* __restrict__ srcs,
                       const __half* __restrict__ hs, const float* __restrict__ dinv,
                       const float* __restrict__ b1, __half* __restrict__ z) {
    unsigned tid = blockIdx.x * blockDim.x + threadIdx.x;
    unsigned node = tid >> 6;
    int f = tid & 63;
    if (node >= N_NODES) return;
    int beg = row_ptr[node], end = row_ptr[node + 1];
    float v = __half2float(hs[(size_t)node * F_H + f]);
    int j = beg;
    for (; j + 8 <= end; j += 8) {
        int s0 = srcs[j],     s1 = srcs[j + 1], s2 = srcs[j + 2], s3 = srcs[j + 3];
        int s4 = srcs[j + 4], s5 = srcs[j + 5], s6 = srcs[j + 6], s7 = srcs[j + 7];
        float a0 = __half2float(hs[(size_t)s0 * F_H + f]);
        float a1 = __half2float(hs[(size_t)s1 * F_H + f]);
        float a2 = __half2float(hs[(size_t)s2 * F_H + f]);
        float a3 = __half2float(hs[(size_t)s3 * F_H + f]);
        float a4 = __half2float(hs[(size_t)s4 * F_H + f]);
        float a5 = __half2float(hs[(size_t)s5 * F_H + f]);
        float a6 = __half2float(hs[(size_t)s6 * F_H + f]);
        float a7 = __half2float(hs[(size_t)s7 * F_H + f]);
        v += ((a0 + a1) + (a2 + a3)) + ((a4 + a5) + (a6 + a7));
    }
    for (; j < end; j++) v += __half2float(hs[(size_t)srcs[j] * F_H + f]);
    z[(size_t)node * F_H + f] = __float2half_rn(fmaxf(dinv[node] * v + b1[f], 0.0f));
}

// ---------------------------------------------------------------------------
// Aggregate L2 + head: out = dot(dinv*agg + b2, Wc) + bc
// ---------------------------------------------------------------------------
__global__ void k_agg2_head(const int* __restrict__ row_ptr, const int* __restrict__ srcs,
                            const __half* __restrict__ hs2, const float* __restrict__ dinv,
                            const float* __restrict__ b2, const float* __restrict__ Wc,
                            const float* __restrict__ bc, float* __restrict__ out) {
    unsigned tid = blockIdx.x * blockDim.x + threadIdx.x;
    unsigned node = tid >> 6;
    int f = tid & 63;
    if (node >= N_NODES) return;
    int beg = row_ptr[node], end = row_ptr[node + 1];
    float v = __half2float(hs2[(size_t)node * F_H + f]);
    int j = beg;
    for (; j + 8 <= end; j += 8) {
        int s0 = srcs[j],     s1 = srcs[j + 1], s2 = srcs[j + 2], s3 = srcs[j + 3];
        int s4 = srcs[j + 4], s5 = srcs[j + 5], s6 = srcs[j + 6], s7 = srcs[j + 7];
        float a0 = __half2float(hs2[(size_t)s0 * F_H + f]);
        float a1 = __half2float(hs2[(size_t)s1 * F_H + f]);
        float a2 = __half2float(hs2[(size_t)s2 * F_H + f]);
        float a3 = __half2float(hs2[(size_t)s3 * F_H + f]);
        float a4 = __half2float(hs2[(size_t)s4 * F_H + f]);
        float a5 = __half2float(hs2[(size_t)s5 * F_H + f]);
        float a6 = __half2float(hs2[(size_t)s6 * F_H + f]);
        float a7 = __half2float(hs2[(size_t)s7 * F_H + f]);
        v += ((a0 + a1) + (a2 + a3)) + ((a4 + a5) + (a6 + a7));
    }
    for (; j < end; j++) v += __half2float(hs2[(size_t)srcs[j] * F_H + f]);
    float r = (dinv[node] * v + b2[f]) * Wc[f];
#pragma unroll
    for (int off = 32; off > 0; off >>= 1)
        r += __shfl_xor(r, off, 64);
    if (f == 0) out[node] = r + bc[0];
}

// ---------------------------------------------------------------------------
extern "C" void kernel_launch(void* const* d_in, const int* in_sizes, int n_in,
                              void* d_out, int out_size, void* d_ws, size_t ws_size,
                              hipStream_t stream) {
    const float* x  = (const float*)d_in[0];
    const int*   ei = (const int*)d_in[1];
    const int*   src = ei;
    const int*   dst = ei + N_EDGES;
    const float* W1 = (const float*)d_in[2];
    const float* b1 = (const float*)d_in[3];
    const float* W2 = (const float*)d_in[4];
    const float* b2 = (const float*)d_in[5];
    const float* Wc = (const float*)d_in[6];
    const float* bc = (const float*)d_in[7];
    float* out = (float*)d_out;

    char* w = (char*)d_ws;
    int*    bcount  = (int*)w;    w += NBUCK * 4;
    int*    bbase   = (int*)w;    w += (NBUCK + 1) * 4;
    int*    bcur    = (int*)w;    w += NBUCK * 4;
    int*    row_ptr = (int*)w;    w += ((size_t)N_NODES + 4) * 4;
    float*  dinv    = (float*)w;  w += (size_t)N_NODES * 4;
    int*    srcs    = (int*)w;    w += (size_t)N_EDGES * 4;
    __half* bufA    = (__half*)w; w += (size_t)N_NODES * F_H * 2;  // hs1 / hs2 (12.8 MB)
    __half* bufB    = (__half*)w; w += (size_t)N_NODES * F_H * 2;  // z        (12.8 MB)
    int*    packT   = (int*)w;    w += (size_t)N_EDGES * 4;        // sort intermediate

    const int TB = 256;
    const int NB_BH = (int)(((long long)N_EDGES + BH_C - 1) / BH_C);  // 196
    const int NB_PA = (int)(((long long)N_EDGES + PA_C - 1) / PA_C);  // 782
    const int NB_G  = (N_NODES + NTB - 1) / NTB;                      // 782

    hipMemsetAsync(bcount, 0, NBUCK * 4, stream);
    k_bhist<<<NB_BH, BH_T, 0, stream>>>(dst, bcount);
    k_bscan<<<1, NBUCK, 0, stream>>>(bcount, bbase, bcur, row_ptr);
    k_partA<<<NB_PA, PA_T, 0, stream>>>(src, dst, bcur, packT);
    k_partB<<<NBUCK, PB_T, 0, stream>>>(bbase, packT, row_ptr, dinv, srcs);

    // layer 1: gemm -> bufA(hs1 fp16), aggregate -> bufB(z fp16)
    k_gemm1<<<NB_G, GT, 0, stream>>>(x, W1, dinv, bufA);
    k_agg1<<<((unsigned)N_NODES * 64 + TB - 1) / TB, TB, 0, stream>>>(row_ptr, srcs, bufA, dinv, b1, bufB);

    // layer 2: gemm bufB -> bufA(hs2 fp16), aggregate+head -> out
    k_gemm2<<<NB_G, GT, 0, stream>>>(bufB, W2, dinv, bufA);
    k_agg2_head<<<((unsigned)N_NODES * 64 + TB - 1) / TB, TB, 0, stream>>>(row_ptr, srcs, bufA, dinv, b2, Wc, bc, out);
}

// Round 7
// 323.270 us; speedup vs baseline: 5.4231x; 1.3268x over previous
//
#include <hip/hip_runtime.h>
#include <hip/hip_bf16.h>
#include <hip/hip_fp16.h>

#define N_NODES 100000
#define N_EDGES 3200000
#define F_IN    128
#define F_H     64

#define NBUCK 256
#define NPB   391            // ceil(N_NODES / NBUCK); last bucket short
#define SRC_BITS 17          // N_NODES < 2^17; pack = (dstLocal<<17)|src

// ---------------------------------------------------------------------------
// Bucket-level histogram: 256 bins, LDS-aggregated (50K global atomics total)
// ---------------------------------------------------------------------------
#define BH_T 256
#define BH_C 16384           // edges per block -> 196 blocks
__global__ __launch_bounds__(BH_T) void k_bhist(const int* __restrict__ dst,
                                                int* __restrict__ bcount) {
    __shared__ int lc[NBUCK];
    int t = threadIdx.x;
    lc[t] = 0;
    __syncthreads();
    long long e0 = (long long)blockIdx.x * BH_C;
    long long e1 = e0 + BH_C; if (e1 > N_EDGES) e1 = N_EDGES;
    for (long long e = e0 + t; e < e1; e += BH_T)
        atomicAdd(&lc[dst[e] / NPB], 1);
    __syncthreads();
    int c = lc[t];
    if (c) atomicAdd(&bcount[t], c);
}

// ---------------------------------------------------------------------------
// Scan of 256 bucket counts -> bucket bases + partA cursors; row_ptr[N]=E
// ---------------------------------------------------------------------------
__global__ __launch_bounds__(NBUCK) void k_bscan(const int* __restrict__ bcount,
                                                 int* __restrict__ bbase,
                                                 int* __restrict__ bcur,
                                                 int* __restrict__ row_ptr) {
    __shared__ int s[NBUCK];
    int t = threadIdx.x;
    int c = bcount[t];
    s[t] = c;
    __syncthreads();
    for (int off = 1; off < NBUCK; off <<= 1) {
        int v = (t >= off) ? s[t - off] : 0;
        __syncthreads();
        s[t] += v;
        __syncthreads();
    }
    int ex = s[t] - c;
    bbase[t] = ex;
    bcur[t]  = ex;
    if (t == NBUCK - 1) {
        bbase[NBUCK] = s[t];             // = N_EDGES
        row_ptr[N_NODES] = s[t];
    }
}

// ---------------------------------------------------------------------------
// wc2 = W2^T Wc (64-vector), c0 = Wc.b2 + bc  — collapses layer2+head
// ---------------------------------------------------------------------------
__global__ __launch_bounds__(64) void k_wc2(const float* __restrict__ W2,
                                            const float* __restrict__ Wc,
                                            const float* __restrict__ b2,
                                            const float* __restrict__ bc,
                                            float* __restrict__ wc2,
                                            float* __restrict__ c0) {
    int k = threadIdx.x;
    float s = 0.0f;
#pragma unroll 8
    for (int f = 0; f < F_H; f++) s += Wc[f] * W2[f * F_H + k];
    wc2[k] = s;
    float p = Wc[k] * b2[k];
#pragma unroll
    for (int off = 32; off > 0; off >>= 1) p += __shfl_xor(p, off, 64);
    if (k == 0) c0[0] = p + bc[0];
}

// ---------------------------------------------------------------------------
// Pass A: partition edges into NBUCK dst-range buckets; emit packed
// (dstLocal<<17)|src words (LDS-staged, coalesced out)
// ---------------------------------------------------------------------------
#define PA_T   256
#define PA_C   4096
#define PA_PER (PA_C / PA_T)   // 16
__global__ __launch_bounds__(PA_T) void k_partA(const int* __restrict__ src,
                                                const int* __restrict__ dst,
                                                int* __restrict__ bucket_cursor,
                                                int* __restrict__ packT) {
    __shared__ int lcount[NBUCK];
    __shared__ int lstart[NBUCK];
    __shared__ int loffs[NBUCK];
    __shared__ int lbase[NBUCK];
    __shared__ int s_pack[PA_C];
    __shared__ unsigned char s_bkt[PA_C];
    __shared__ int ltot;
    int t = threadIdx.x;
    long long e0 = (long long)blockIdx.x * PA_C;
    if (t < NBUCK) lcount[t] = 0;
    __syncthreads();
    int ep[PA_PER];
    short eb[PA_PER];
#pragma unroll
    for (int i = 0; i < PA_PER; i++) {
        long long e = e0 + i * PA_T + t;
        if (e < N_EDGES) {
            int es = src[e], ed = dst[e];
            int b = ed / NPB;
            eb[i] = (short)b;
            ep[i] = ((ed - b * NPB) << SRC_BITS) | es;
            atomicAdd(&lcount[b], 1);
        } else eb[i] = -1;
    }
    __syncthreads();
    // exclusive scan of lcount (256) by wave 0: 4 serial/lane + shfl scan
    if (t < 64) {
        int base = t * 4;
        int c0 = lcount[base], c1 = lcount[base + 1], c2 = lcount[base + 2], c3 = lcount[base + 3];
        int ssum = c0 + c1 + c2 + c3;
        int sc = ssum;
#pragma unroll
        for (int off = 1; off < 64; off <<= 1) {
            int v = __shfl_up(sc, off, 64);
            if (t >= off) sc += v;
        }
        int ex = sc - ssum;
        lstart[base]     = ex;
        lstart[base + 1] = ex + c0;
        lstart[base + 2] = ex + c0 + c1;
        lstart[base + 3] = ex + c0 + c1 + c2;
        if (t == 63) ltot = sc;
    }
    __syncthreads();
    if (t < NBUCK) {
        loffs[t] = lstart[t];
        int c = lcount[t];
        lbase[t] = c ? atomicAdd(&bucket_cursor[t], c) : 0;
    }
    __syncthreads();
#pragma unroll
    for (int i = 0; i < PA_PER; i++) {
        if (eb[i] >= 0) {
            int idx = atomicAdd(&loffs[eb[i]], 1);
            s_pack[idx] = ep[i];
            s_bkt[idx] = (unsigned char)eb[i];
        }
    }
    __syncthreads();
    int tot = ltot;
    for (int i = t; i < tot; i += PA_T) {
        int b = s_bkt[i];
        int addr = lbase[b] + (i - lstart[b]);
        packT[addr] = s_pack[i];
    }
}

// ---------------------------------------------------------------------------
// Pass B: per-bucket LDS counting sort of packed words -> srcs[] segment,
// plus derives row_ptr[node] and dinv[node] from the local histogram.
// ---------------------------------------------------------------------------
#define PB_T   1024
#define PB_CAP 16384
__global__ __launch_bounds__(PB_T) void k_partB(const int* __restrict__ bbase,
                                                const int* __restrict__ packT,
                                                int* __restrict__ row_ptr,
                                                float* __restrict__ dinv,
                                                int* __restrict__ srcs) {
    __shared__ int lhist[NPB];
    __shared__ int lcur[NPB];
    __shared__ int s_out[PB_CAP];
    int b = blockIdx.x;
    int node0 = b * NPB;
    int node1 = min(node0 + NPB, N_NODES);
    int nloc = node1 - node0;
    int beg = bbase[b];
    int end = bbase[b + 1];
    int len = end - beg;
    int t = threadIdx.x;
    const int SMASK = (1 << SRC_BITS) - 1;

    for (int i = t; i < NPB; i += PB_T) lhist[i] = 0;
    __syncthreads();
    for (int i = t; i < len; i += PB_T)
        atomicAdd(&lhist[packT[beg + i] >> SRC_BITS], 1);
    __syncthreads();
    if (t < 64) {   // exclusive scan of 391 counters: 7/lane + shfl
        int base = t * 7;
        int c[7]; int ssum = 0;
#pragma unroll
        for (int j = 0; j < 7; j++) {
            int idx = base + j;
            c[j] = (idx < NPB) ? lhist[idx] : 0;
            ssum += c[j];
        }
        int sc = ssum;
#pragma unroll
        for (int off = 1; off < 64; off <<= 1) {
            int v = __shfl_up(sc, off, 64);
            if (t >= off) sc += v;
        }
        int ex = sc - ssum;
#pragma unroll
        for (int j = 0; j < 7; j++) {
            int idx = base + j;
            if (idx < NPB) lcur[idx] = ex;
            ex += c[j];
        }
    }
    __syncthreads();
    // derive row_ptr / dinv from local exclusive prefix (before lcur mutates)
    for (int i = t; i < nloc; i += PB_T) {
        row_ptr[node0 + i] = beg + lcur[i];
        dinv[node0 + i] = rsqrtf((float)(lhist[i] + 1));
    }
    __syncthreads();
    if (len <= PB_CAP) {
        for (int i = t; i < len; i += PB_T) {
            int pk = packT[beg + i];
            int idx = atomicAdd(&lcur[pk >> SRC_BITS], 1);
            s_out[idx] = pk & SMASK;
        }
        __syncthreads();
        for (int i = t; i < len; i += PB_T)
            srcs[beg + i] = s_out[i];
    } else {    // statistically never (34 sigma): direct global scatter
        for (int i = t; i < len; i += PB_T) {
            int pk = packT[beg + i];
            int idx = atomicAdd(&lcur[pk >> SRC_BITS], 1);
            srcs[beg + idx] = pk & SMASK;
        }
    }
}

// ---------------------------------------------------------------------------
// Layer-1 GEMM: hs16 = fp16( (x @ W1^T) * dinv )
// Register-tiled: block = 256 thr (4 waves), 128 nodes/block.
// Wave tile 64f x 32n; lane(fi 0..15, ni 0..3) owns 4f x 8n accumulator.
// LDS k-major: wT[k][f] (stride 68), xT[k][n] (stride 128) -> conflict-free.
// ---------------------------------------------------------------------------
#define GT   256
#define NTB  128     // nodes per block
#define KT   64      // k-tile (2 passes for F_IN=128)
#define WTS  68      // wT stride (words)

__global__ __launch_bounds__(GT) void k_gemm1(const float* __restrict__ x,
                                              const float* __restrict__ W1,
                                              const float* __restrict__ dinv,
                                              __half* __restrict__ hs) {
    __shared__ float wT[KT * WTS];     // 17.4 KB
    __shared__ float xT[KT * NTB];     // 32 KB
    int t = threadIdx.x;
    int node0 = blockIdx.x * NTB;
    int lane = t & 63, wv = t >> 6;
    int fi = lane & 15, ni = lane >> 4;
    int n0 = wv * 32 + ni * 8;         // this lane's first node offset in block

    float acc[4][8];
#pragma unroll
    for (int r = 0; r < 4; r++)
#pragma unroll
        for (int c = 0; c < 8; c++) acc[r][c] = 0.0f;

    for (int p = 0; p < 2; p++) {
        int k0 = p * KT;
        if (p) __syncthreads();        // previous pass reads complete
        // stage W1 chunk (transposed)
        {
            int f = t & 63, kq = t >> 6;
            const float4* wp = (const float4*)&W1[(size_t)f * F_IN + k0 + kq * 16];
#pragma unroll
            for (int j = 0; j < 4; j++) {
                float4 v = wp[j];
                int kl = kq * 16 + 4 * j;
                wT[(kl + 0) * WTS + f] = v.x;
                wT[(kl + 1) * WTS + f] = v.y;
                wT[(kl + 2) * WTS + f] = v.z;
                wT[(kl + 3) * WTS + f] = v.w;
            }
        }
        // stage x chunk (transposed)
        {
            int n = t & 127, half = t >> 7;
            int node = node0 + n;
#pragma unroll
            for (int j = 0; j < 8; j++) {
                int ku = half * 8 + j;                 // 0..15
                float4 v = make_float4(0.f, 0.f, 0.f, 0.f);
                if (node < N_NODES)
                    v = *(const float4*)&x[(size_t)node * F_IN + k0 + 4 * ku];
                int kl = 4 * ku;
                xT[(kl + 0) * NTB + n] = v.x;
                xT[(kl + 1) * NTB + n] = v.y;
                xT[(kl + 2) * NTB + n] = v.z;
                xT[(kl + 3) * NTB + n] = v.w;
            }
        }
        __syncthreads();
#pragma unroll 8
        for (int k = 0; k < KT; k++) {
            float4 wf = *(const float4*)&wT[k * WTS + fi * 4];
            float4 xa = *(const float4*)&xT[k * NTB + n0];
            float4 xb = *(const float4*)&xT[k * NTB + n0 + 4];
            float wr[4] = {wf.x, wf.y, wf.z, wf.w};
            float xv[8] = {xa.x, xa.y, xa.z, xa.w, xb.x, xb.y, xb.z, xb.w};
#pragma unroll
            for (int r = 0; r < 4; r++)
#pragma unroll
                for (int c = 0; c < 8; c++) acc[r][c] += wr[r] * xv[c];
        }
    }
    // epilogue: scale by dinv, fp16 pack, 8 B stores
#pragma unroll
    for (int c = 0; c < 8; c++) {
        int node = node0 + n0 + c;
        if (node < N_NODES) {
            float dv = dinv[node];
            __half2 h0 = __floats2half2_rn(acc[0][c] * dv, acc[1][c] * dv);
            __half2 h1 = __floats2half2_rn(acc[2][c] * dv, acc[3][c] * dv);
            __half2* p = (__half2*)&hs[(size_t)node * F_H + fi * 4];
            p[0] = h0; p[1] = h1;
        }
    }
}

// ---------------------------------------------------------------------------
// Aggregate L1 + epilogue + collapsed layer2/head projection:
//   v   = self + sum_neighbors          (128 B/edge gather, fp16)
//   z_f = relu(dinv*v + b1)             (in registers, never stored)
//   q   = dinv * sum_f wc2[f]*z_f       (wave reduce, one float per node)
// ---------------------------------------------------------------------------
__global__ void k_agg1q(const int* __restrict__ row_ptr, const int* __restrict__ srcs,
                        const __half* __restrict__ hs, const float* __restrict__ dinv,
                        const float* __restrict__ b1, const float* __restrict__ wc2,
                        float* __restrict__ q) {
    unsigned tid = blockIdx.x * blockDim.x + threadIdx.x;
    unsigned node = tid >> 6;
    int f = tid & 63;
    if (node >= N_NODES) return;
    int beg = row_ptr[node], end = row_ptr[node + 1];
    float v = __half2float(hs[(size_t)node * F_H + f]);
    int j = beg;
    for (; j + 8 <= end; j += 8) {
        int s0 = srcs[j],     s1 = srcs[j + 1], s2 = srcs[j + 2], s3 = srcs[j + 3];
        int s4 = srcs[j + 4], s5 = srcs[j + 5], s6 = srcs[j + 6], s7 = srcs[j + 7];
        float a0 = __half2float(hs[(size_t)s0 * F_H + f]);
        float a1 = __half2float(hs[(size_t)s1 * F_H + f]);
        float a2 = __half2float(hs[(size_t)s2 * F_H + f]);
        float a3 = __half2float(hs[(size_t)s3 * F_H + f]);
        float a4 = __half2float(hs[(size_t)s4 * F_H + f]);
        float a5 = __half2float(hs[(size_t)s5 * F_H + f]);
        float a6 = __half2float(hs[(size_t)s6 * F_H + f]);
        float a7 = __half2float(hs[(size_t)s7 * F_H + f]);
        v += ((a0 + a1) + (a2 + a3)) + ((a4 + a5) + (a6 + a7));
    }
    for (; j < end; j++) v += __half2float(hs[(size_t)srcs[j] * F_H + f]);
    float dv = dinv[node];
    float z = fmaxf(dv * v + b1[f], 0.0f);
    float p = z * wc2[f];
#pragma unroll
    for (int off = 32; off > 0; off >>= 1)
        p += __shfl_xor(p, off, 64);
    if (f == 0) q[node] = dv * p;
}

// ---------------------------------------------------------------------------
// Final: out[d] = dinv[d] * (q[d] + sum_{s->d} q[s]) + c0
// one thread per node; q (400 KB) is L2-resident
// ---------------------------------------------------------------------------
__global__ void k_final(const int* __restrict__ row_ptr, const int* __restrict__ srcs,
                        const float* __restrict__ q, const float* __restrict__ dinv,
                        const float* __restrict__ c0, float* __restrict__ out) {
    int node = blockIdx.x * blockDim.x + threadIdx.x;
    if (node >= N_NODES) return;
    int beg = row_ptr[node], end = row_ptr[node + 1];
    float acc = q[node];
    int j = beg;
    for (; j + 4 <= end; j += 4) {
        int s0 = srcs[j], s1 = srcs[j + 1], s2 = srcs[j + 2], s3 = srcs[j + 3];
        float a0 = q[s0], a1 = q[s1], a2 = q[s2], a3 = q[s3];
        acc += (a0 + a1) + (a2 + a3);
    }
    for (; j < end; j++) acc += q[srcs[j]];
    out[node] = dinv[node] * acc + c0[0];
}

// ---------------------------------------------------------------------------
extern "C" void kernel_launch(void* const* d_in, const int* in_sizes, int n_in,
                              void* d_out, int out_size, void* d_ws, size_t ws_size,
                              hipStream_t stream) {
    const float* x  = (const float*)d_in[0];
    const int*   ei = (const int*)d_in[1];
    const int*   src = ei;
    const int*   dst = ei + N_EDGES;
    const float* W1 = (const float*)d_in[2];
    const float* b1 = (const float*)d_in[3];
    const float* W2 = (const float*)d_in[4];
    const float* b2 = (const float*)d_in[5];
    const float* Wc = (const float*)d_in[6];
    const float* bc = (const float*)d_in[7];
    float* out = (float*)d_out;

    char* w = (char*)d_ws;
    int*    bcount  = (int*)w;    w += NBUCK * 4;
    int*    bbase   = (int*)w;    w += (NBUCK + 1) * 4;
    int*    bcur    = (int*)w;    w += NBUCK * 4;
    float*  wc2     = (float*)w;  w += 64 * 4;
    float*  c0      = (float*)w;  w += 4 * 4;
    int*    row_ptr = (int*)w;    w += ((size_t)N_NODES + 4) * 4;
    float*  dinv    = (float*)w;  w += (size_t)N_NODES * 4;
    float*  q       = (float*)w;  w += (size_t)N_NODES * 4;
    int*    srcs    = (int*)w;    w += (size_t)N_EDGES * 4;
    __half* bufA    = (__half*)w; w += (size_t)N_NODES * F_H * 2;  // hs1 (12.8 MB)
    int*    packT   = (int*)w;    w += (size_t)N_EDGES * 4;        // sort intermediate

    const int TB = 256;
    const int NB_BH = (int)(((long long)N_EDGES + BH_C - 1) / BH_C);  // 196
    const int NB_PA = (int)(((long long)N_EDGES + PA_C - 1) / PA_C);  // 782
    const int NB_G  = (N_NODES + NTB - 1) / NTB;                      // 782

    hipMemsetAsync(bcount, 0, NBUCK * 4, stream);
    k_bhist<<<NB_BH, BH_T, 0, stream>>>(dst, bcount);
    k_bscan<<<1, NBUCK, 0, stream>>>(bcount, bbase, bcur, row_ptr);
    k_wc2  <<<1, 64, 0, stream>>>(W2, Wc, b2, bc, wc2, c0);
    k_partA<<<NB_PA, PA_T, 0, stream>>>(src, dst, bcur, packT);
    k_partB<<<NBUCK, PB_T, 0, stream>>>(bbase, packT, row_ptr, dinv, srcs);

    // layer 1: gemm -> bufA(hs1 fp16), aggregate+relu+project -> q
    k_gemm1<<<NB_G, GT, 0, stream>>>(x, W1, dinv, bufA);
    k_agg1q<<<((unsigned)N_NODES * 64 + TB - 1) / TB, TB, 0, stream>>>(row_ptr, srcs, bufA, dinv, b1, wc2, q);

    // collapsed layer 2 + head: scalar gather over q
    k_final<<<(N_NODES + TB - 1) / TB, TB, 0, stream>>>(row_ptr, srcs, q, dinv, c0, out);
}